// Round 1
// baseline (334.271 us; speedup 1.0000x reference)
//
#include <hip/hip_runtime.h>

typedef _Float16 f16;
typedef __attribute__((ext_vector_type(4))) float    f32x4;
typedef __attribute__((ext_vector_type(8))) _Float16 f16x8;
typedef __attribute__((ext_vector_type(4))) _Float16 f16x4;

static constexpr int B_ = 2, N_ = 2048, E_ = 1024, H_ = 16, D_ = 64;
static constexpr int M_ = B_ * N_;   // 4096 rows

#define MFMA16(a, b, c) __builtin_amdgcn_mfma_f32_16x16x32_f16(a, b, c, 0, 0, 0)

// ---------------------------------------------------------------------------
// Kernel 1: cast the 4 weight matrices (fp32, [E,E] row-major = [n_out, k]) to f16
// Layout in dst: Wq | Wk | Wv | Wo, each E*E elements.
// ---------------------------------------------------------------------------
__global__ __launch_bounds__(256) void castw_kernel(
    const float* __restrict__ Wq, const float* __restrict__ Wk,
    const float* __restrict__ Wv, const float* __restrict__ Wo,
    f16* __restrict__ dst)
{
    const int i = (blockIdx.x * 256 + threadIdx.x) * 4;   // elem idx in 4*E*E space
    const int which = i >> 20;                            // E*E = 2^20
    const float* s = (which == 0) ? Wq : (which == 1) ? Wk : (which == 2) ? Wv : Wo;
    const int j = i & (E_ * E_ - 1);
    const f32x4 f = *(const f32x4*)&s[j];
    f16x4 o;
    o[0] = (f16)f[0]; o[1] = (f16)f[1]; o[2] = (f16)f[2]; o[3] = (f16)f[3];
    *(f16x4*)&dst[i] = o;
}

// ---------------------------------------------------------------------------
// Kernel 2: projection GEMM.  C[m,n] = A[m,:] . W[n,:] + bias[n]
//   A: fp32 [4096, 1024] (q/k/v), W: f16 [1024,1024] (row n = output feature)
//   z = blockIdx.z selects q/k/v.
//   Epilogue: q -> qh[b,h,n,d] (scaled by 1/8), k -> kh[b,h,n,d], v -> vt[b,h,d,n]
// Tile: BM=BN=128, BK=32; 4 waves in 2x2; per-wave 64x64 = 4x4 MFMA frags.
// ---------------------------------------------------------------------------
__global__ __launch_bounds__(256) void proj_gemm(
    const float* __restrict__ q, const float* __restrict__ k, const float* __restrict__ v,
    const f16* __restrict__ Wb,
    const float* __restrict__ bq, const float* __restrict__ bk, const float* __restrict__ bv,
    f16* __restrict__ qh, f16* __restrict__ kh, f16* __restrict__ vt)
{
    const int z = blockIdx.z;
    const float* A    = (z == 0) ? q  : (z == 1) ? k  : v;
    const f16*   W    = Wb + (size_t)z * E_ * E_;
    const float* bias = (z == 0) ? bq : (z == 1) ? bk : bv;

    __shared__ f16 As[128][40];   // +8 pad (16B): 2-way-max bank aliasing on b128 reads
    __shared__ f16 Bs[128][40];

    const int tid  = threadIdx.x;
    const int lane = tid & 63, w = tid >> 6;
    const int lr = lane & 15, lg = lane >> 4;
    const int wm = (w >> 1) * 64, wn = (w & 1) * 64;
    const int m0 = blockIdx.y * 128, n0 = blockIdx.x * 128;

    const int srow = tid >> 1;           // 0..127
    const int skh  = (tid & 1) * 16;     // 0 or 16

    f32x4 acc[4][4];
#pragma unroll
    for (int i = 0; i < 4; i++)
#pragma unroll
        for (int j = 0; j < 4; j++) acc[i][j] = (f32x4){0.f, 0.f, 0.f, 0.f};

    for (int k0 = 0; k0 < E_; k0 += 32) {
        __syncthreads();
        // stage A tile (fp32 -> f16): each thread 1 row-half (16 elems)
        {
            const float* src = &A[(size_t)(m0 + srow) * E_ + k0 + skh];
            const f32x4 f0 = *(const f32x4*)(src + 0);
            const f32x4 f1 = *(const f32x4*)(src + 4);
            const f32x4 f2 = *(const f32x4*)(src + 8);
            const f32x4 f3 = *(const f32x4*)(src + 12);
            f16x8 b0, b1;
#pragma unroll
            for (int t = 0; t < 4; t++) { b0[t] = (f16)f0[t]; b0[4 + t] = (f16)f1[t]; }
#pragma unroll
            for (int t = 0; t < 4; t++) { b1[t] = (f16)f2[t]; b1[4 + t] = (f16)f3[t]; }
            *(f16x8*)&As[srow][skh]     = b0;
            *(f16x8*)&As[srow][skh + 8] = b1;
        }
        // stage B tile (f16 weights)
        {
            const f16* src = &W[(size_t)(n0 + srow) * E_ + k0 + skh];
            *(f16x8*)&Bs[srow][skh]     = *(const f16x8*)(src);
            *(f16x8*)&Bs[srow][skh + 8] = *(const f16x8*)(src + 8);
        }
        __syncthreads();

        f16x8 af[4], bfr[4];
#pragma unroll
        for (int ms = 0; ms < 4; ms++) af[ms]  = *(const f16x8*)&As[wm + ms * 16 + lr][lg * 8];
#pragma unroll
        for (int ns = 0; ns < 4; ns++) bfr[ns] = *(const f16x8*)&Bs[wn + ns * 16 + lr][lg * 8];
#pragma unroll
        for (int ms = 0; ms < 4; ms++)
#pragma unroll
            for (int ns = 0; ns < 4; ns++)
                acc[ms][ns] = MFMA16(af[ms], bfr[ns], acc[ms][ns]);
    }

    // epilogue: C/D layout col = lane&15, row = (lane>>4)*4 + r
    const float oscale = (z == 0) ? 0.125f : 1.0f;   // 1/sqrt(64), applied after bias
#pragma unroll
    for (int ms = 0; ms < 4; ms++) {
        const int mbase = m0 + wm + ms * 16 + lg * 4;
#pragma unroll
        for (int ns = 0; ns < 4; ns++) {
            const int n  = n0 + wn + ns * 16 + lr;
            const float bn = bias[n];
            const int hh = n >> 6, dd = n & 63;
#pragma unroll
            for (int r = 0; r < 4; r++) {
                const float val = (acc[ms][ns][r] + bn) * oscale;
                const int mm = mbase + r;
                const int bb = mm >> 11;            // / N_
                const int nn = mm & (N_ - 1);
                if (z == 2) {
                    vt[((size_t)(bb * H_ + hh) * D_ + dd) * N_ + nn] = (f16)val;
                } else {
                    f16* dst = (z == 0) ? qh : kh;
                    dst[((size_t)(bb * H_ + hh) * N_ + nn) * D_ + dd] = (f16)val;
                }
            }
        }
    }
}

// ---------------------------------------------------------------------------
// Kernel 3: flash attention.
//  grid (32 q-tiles, 32 b*h); block = 256 = 4 waves; wave owns 16 q-rows.
//  qh/kh: [bh][n][64] f16 (q pre-scaled); vt: [bh][64][n] f16.
//  Online softmax with C-layout stats; P transposed via wave-private LDS.
// ---------------------------------------------------------------------------
__global__ __launch_bounds__(256) void attn_kernel(
    const f16* __restrict__ qh, const f16* __restrict__ kh,
    const f16* __restrict__ vt, f16* __restrict__ ao)
{
    const int qt = blockIdx.x;          // 0..31
    const int bh = blockIdx.y;          // 0..31
    const int tid = threadIdx.x;
    const int w = tid >> 6, lane = tid & 63;
    const int lr = lane & 15, lg = lane >> 4;

    const f16* qp = qh + (size_t)bh * N_ * D_;
    const f16* kp = kh + (size_t)bh * N_ * D_;
    const f16* vp = vt + (size_t)bh * D_ * N_;

    const int qrow0 = qt * 64 + w * 16;

    const f16x8 qf0 = *(const f16x8*)&qp[(size_t)(qrow0 + lr) * D_ + lg * 8];
    const f16x8 qf1 = *(const f16x8*)&qp[(size_t)(qrow0 + lr) * D_ + 32 + lg * 8];

    f32x4 acc0 = {0.f,0.f,0.f,0.f}, acc1 = {0.f,0.f,0.f,0.f};
    f32x4 acc2 = {0.f,0.f,0.f,0.f}, acc3 = {0.f,0.f,0.f,0.f};
    float mrun[4], lrun[4];
#pragma unroll
    for (int r = 0; r < 4; r++) { mrun[r] = -1e30f; lrun[r] = 0.f; }

    __shared__ f16 plds[4][16][72];   // per-wave P tile, 16 q-rows x 64 kv (+8 pad)

    for (int kv0 = 0; kv0 < N_; kv0 += 64) {
        // ---- S = Q K^T  (4 col-subtiles of 16) ----
        f32x4 s0 = {0.f,0.f,0.f,0.f}, s1 = {0.f,0.f,0.f,0.f};
        f32x4 s2 = {0.f,0.f,0.f,0.f}, s3 = {0.f,0.f,0.f,0.f};
        {
            const f16* kb = &kp[(size_t)(kv0 + lr) * D_ + lg * 8];
#define QKSTEP(c, sc)                                                 \
            {                                                         \
                f16x8 kf0 = *(const f16x8*)(kb + (c) * 16 * D_);      \
                f16x8 kf1 = *(const f16x8*)(kb + (c) * 16 * D_ + 32); \
                sc = MFMA16(qf0, kf0, sc);                            \
                sc = MFMA16(qf1, kf1, sc);                            \
            }
            QKSTEP(0, s0) QKSTEP(1, s1) QKSTEP(2, s2) QKSTEP(3, s3)
#undef QKSTEP
        }
        // ---- online softmax (rows = lg*4 + r, cols = lr across 16-lane group) ----
        float alpha[4];
#pragma unroll
        for (int r = 0; r < 4; r++) {
            float mx = fmaxf(fmaxf(s0[r], s1[r]), fmaxf(s2[r], s3[r]));
#pragma unroll
            for (int off = 1; off < 16; off <<= 1) mx = fmaxf(mx, __shfl_xor(mx, off));
            const float mnew = fmaxf(mrun[r], mx);
            alpha[r] = __expf(mrun[r] - mnew);
            mrun[r] = mnew;
            const float p0 = __expf(s0[r] - mnew), p1 = __expf(s1[r] - mnew);
            const float p2 = __expf(s2[r] - mnew), p3 = __expf(s3[r] - mnew);
            s0[r] = p0; s1[r] = p1; s2[r] = p2; s3[r] = p3;
            float sm = p0 + p1 + p2 + p3;
#pragma unroll
            for (int off = 1; off < 16; off <<= 1) sm += __shfl_xor(sm, off);
            lrun[r] = lrun[r] * alpha[r] + sm;
        }
#pragma unroll
        for (int r = 0; r < 4; r++) {
            acc0[r] *= alpha[r]; acc1[r] *= alpha[r];
            acc2[r] *= alpha[r]; acc3[r] *= alpha[r];
        }
        // ---- P (C-layout) -> LDS (A-layout source) ----
#pragma unroll
        for (int r = 0; r < 4; r++) {
            plds[w][lg * 4 + r][ 0 + lr] = (f16)s0[r];
            plds[w][lg * 4 + r][16 + lr] = (f16)s1[r];
            plds[w][lg * 4 + r][32 + lr] = (f16)s2[r];
            plds[w][lg * 4 + r][48 + lr] = (f16)s3[r];
        }
        // wave-local LDS: DS ops are in-order within a wave; stop compiler reordering
        asm volatile("s_waitcnt lgkmcnt(0)" ::: "memory");
        // ---- O += P V ----
        const f16* vb = &vp[(size_t)lr * N_ + kv0 + lg * 8];
#pragma unroll
        for (int kc = 0; kc < 2; kc++) {
            const f16x8 pa = *(const f16x8*)&plds[w][lr][kc * 32 + lg * 8];
            const f16x8 vf0 = *(const f16x8*)(vb + kc * 32 + (size_t)0  * 16 * N_);
            const f16x8 vf1 = *(const f16x8*)(vb + kc * 32 + (size_t)1  * 16 * N_);
            const f16x8 vf2 = *(const f16x8*)(vb + kc * 32 + (size_t)2  * 16 * N_);
            const f16x8 vf3 = *(const f16x8*)(vb + kc * 32 + (size_t)3  * 16 * N_);
            acc0 = MFMA16(pa, vf0, acc0);
            acc1 = MFMA16(pa, vf1, acc1);
            acc2 = MFMA16(pa, vf2, acc2);
            acc3 = MFMA16(pa, vf3, acc3);
        }
    }

    // ---- epilogue: ao[b, qrow, h*64 + d] f16 ----
    const int b = bh >> 4, h = bh & 15;
#pragma unroll
    for (int r = 0; r < 4; r++) {
        const float inv = 1.0f / lrun[r];
        const int qrow = qrow0 + lg * 4 + r;
        f16* dst = &ao[(size_t)(b * N_ + qrow) * E_ + h * 64 + lr];
        dst[ 0] = (f16)(acc0[r] * inv);
        dst[16] = (f16)(acc1[r] * inv);
        dst[32] = (f16)(acc2[r] * inv);
        dst[48] = (f16)(acc3[r] * inv);
    }
}

// ---------------------------------------------------------------------------
// Kernel 4: output GEMM.  out[m,n] = ao[m,:] . Wo[n,:] + bo[n]   (fp32 out)
// ---------------------------------------------------------------------------
__global__ __launch_bounds__(256) void out_gemm(
    const f16* __restrict__ ao, const f16* __restrict__ Wo,
    const float* __restrict__ bo, float* __restrict__ out)
{
    __shared__ f16 As[128][40];
    __shared__ f16 Bs[128][40];

    const int tid  = threadIdx.x;
    const int lane = tid & 63, w = tid >> 6;
    const int lr = lane & 15, lg = lane >> 4;
    const int wm = (w >> 1) * 64, wn = (w & 1) * 64;
    const int m0 = blockIdx.y * 128, n0 = blockIdx.x * 128;

    const int srow = tid >> 1;
    const int skh  = (tid & 1) * 16;

    f32x4 acc[4][4];
#pragma unroll
    for (int i = 0; i < 4; i++)
#pragma unroll
        for (int j = 0; j < 4; j++) acc[i][j] = (f32x4){0.f, 0.f, 0.f, 0.f};

    for (int k0 = 0; k0 < E_; k0 += 32) {
        __syncthreads();
        {
            const f16* src = &ao[(size_t)(m0 + srow) * E_ + k0 + skh];
            *(f16x8*)&As[srow][skh]     = *(const f16x8*)(src);
            *(f16x8*)&As[srow][skh + 8] = *(const f16x8*)(src + 8);
        }
        {
            const f16* src = &Wo[(size_t)(n0 + srow) * E_ + k0 + skh];
            *(f16x8*)&Bs[srow][skh]     = *(const f16x8*)(src);
            *(f16x8*)&Bs[srow][skh + 8] = *(const f16x8*)(src + 8);
        }
        __syncthreads();

        f16x8 af[4], bfr[4];
#pragma unroll
        for (int ms = 0; ms < 4; ms++) af[ms]  = *(const f16x8*)&As[wm + ms * 16 + lr][lg * 8];
#pragma unroll
        for (int ns = 0; ns < 4; ns++) bfr[ns] = *(const f16x8*)&Bs[wn + ns * 16 + lr][lg * 8];
#pragma unroll
        for (int ms = 0; ms < 4; ms++)
#pragma unroll
            for (int ns = 0; ns < 4; ns++)
                acc[ms][ns] = MFMA16(af[ms], bfr[ns], acc[ms][ns]);
    }

#pragma unroll
    for (int ms = 0; ms < 4; ms++) {
        const int mbase = m0 + wm + ms * 16 + lg * 4;
#pragma unroll
        for (int ns = 0; ns < 4; ns++) {
            const int n = n0 + wn + ns * 16 + lr;
            const float bn = bo[n];
#pragma unroll
            for (int r = 0; r < 4; r++) {
                out[(size_t)(mbase + r) * E_ + n] = acc[ms][ns][r] + bn;
            }
        }
    }
}

// ---------------------------------------------------------------------------
extern "C" void kernel_launch(void* const* d_in, const int* in_sizes, int n_in,
                              void* d_out, int out_size, void* d_ws, size_t ws_size,
                              hipStream_t stream) {
    const float* q  = (const float*)d_in[0];
    const float* k  = (const float*)d_in[1];
    const float* v  = (const float*)d_in[2];
    const float* Wq = (const float*)d_in[3];
    const float* bq = (const float*)d_in[4];
    const float* Wk = (const float*)d_in[5];
    const float* bk = (const float*)d_in[6];
    const float* Wv = (const float*)d_in[7];
    const float* bv = (const float*)d_in[8];
    const float* Wo = (const float*)d_in[9];
    const float* bo = (const float*)d_in[10];
    float* out = (float*)d_out;

    char* ws = (char*)d_ws;
    f16* Wb = (f16*)ws;                                   //  8 MB: Wq|Wk|Wv|Wo f16
    f16* qh = (f16*)(ws + (size_t) 8 * 1024 * 1024);      //  8 MB [B,H,N,D]
    f16* kh = (f16*)(ws + (size_t)16 * 1024 * 1024);      //  8 MB [B,H,N,D]
    f16* vt = (f16*)(ws + (size_t)24 * 1024 * 1024);      //  8 MB [B,H,D,N]
    f16* ao = (f16*)(ws + (size_t)32 * 1024 * 1024);      //  8 MB [B,N,E]

    castw_kernel<<<4096, 256, 0, stream>>>(Wq, Wk, Wv, Wo, Wb);
    proj_gemm<<<dim3(8, 32, 3), 256, 0, stream>>>(q, k, v, Wb, bq, bk, bv, qh, kh, vt);
    attn_kernel<<<dim3(32, 32), 256, 0, stream>>>(qh, kh, vt, ao);
    out_gemm<<<dim3(8, 32), 256, 0, stream>>>(ao, Wb + (size_t)3 * E_ * E_, bo, out);
}

// Round 2
// 206.962 us; speedup vs baseline: 1.6151x; 1.6151x over previous
//
#include <hip/hip_runtime.h>

typedef _Float16 f16;
typedef __attribute__((ext_vector_type(4))) float    f32x4;
typedef __attribute__((ext_vector_type(8))) _Float16 f16x8;
typedef __attribute__((ext_vector_type(4))) _Float16 f16x4;

static constexpr int B_ = 2, N_ = 2048, E_ = 1024, H_ = 16, D_ = 64;
static constexpr int M_ = B_ * N_;   // 4096 rows

#define MFMA16(a, b, c) __builtin_amdgcn_mfma_f32_16x16x32_f16(a, b, c, 0, 0, 0)

// q-projection scale: 1/sqrt(D) * log2(e)  (softmax done in exp2 domain)
#define QSCALE 0.18033688011112042f

// ---------------------------------------------------------------------------
// Kernel 1: cast the 4 weight matrices (fp32, [E,E] row-major) to f16.
// ---------------------------------------------------------------------------
__global__ __launch_bounds__(256) void castw_kernel(
    const float* __restrict__ Wq, const float* __restrict__ Wk,
    const float* __restrict__ Wv, const float* __restrict__ Wo,
    f16* __restrict__ dst)
{
    const int i = (blockIdx.x * 256 + threadIdx.x) * 4;
    const int which = i >> 20;                            // E*E = 2^20
    const float* s = (which == 0) ? Wq : (which == 1) ? Wk : (which == 2) ? Wv : Wo;
    const int j = i & (E_ * E_ - 1);
    const f32x4 f = *(const f32x4*)&s[j];
    f16x4 o;
    o[0] = (f16)f[0]; o[1] = (f16)f[1]; o[2] = (f16)f[2]; o[3] = (f16)f[3];
    *(f16x4*)&dst[i] = o;
}

// ---------------------------------------------------------------------------
// Kernel 2: projection GEMM.  C[m,n] = A[m,:] . W[n,:] + bias[n]
//   Epilogue: q -> qh[b,h,n,d] (scaled by QSCALE), k -> kh, v -> vt[b,h,d,n]
// ---------------------------------------------------------------------------
__global__ __launch_bounds__(256) void proj_gemm(
    const float* __restrict__ q, const float* __restrict__ k, const float* __restrict__ v,
    const f16* __restrict__ Wb,
    const float* __restrict__ bq, const float* __restrict__ bk, const float* __restrict__ bv,
    f16* __restrict__ qh, f16* __restrict__ kh, f16* __restrict__ vt)
{
    const int z = blockIdx.z;
    const float* A    = (z == 0) ? q  : (z == 1) ? k  : v;
    const f16*   W    = Wb + (size_t)z * E_ * E_;
    const float* bias = (z == 0) ? bq : (z == 1) ? bk : bv;

    __shared__ f16 As[128][40];
    __shared__ f16 Bs[128][40];

    const int tid  = threadIdx.x;
    const int lane = tid & 63, w = tid >> 6;
    const int lr = lane & 15, lg = lane >> 4;
    const int wm = (w >> 1) * 64, wn = (w & 1) * 64;
    const int m0 = blockIdx.y * 128, n0 = blockIdx.x * 128;

    const int srow = tid >> 1;
    const int skh  = (tid & 1) * 16;

    f32x4 acc[4][4];
#pragma unroll
    for (int i = 0; i < 4; i++)
#pragma unroll
        for (int j = 0; j < 4; j++) acc[i][j] = (f32x4){0.f, 0.f, 0.f, 0.f};

    for (int k0 = 0; k0 < E_; k0 += 32) {
        __syncthreads();
        {
            const float* src = &A[(size_t)(m0 + srow) * E_ + k0 + skh];
            const f32x4 f0 = *(const f32x4*)(src + 0);
            const f32x4 f1 = *(const f32x4*)(src + 4);
            const f32x4 f2 = *(const f32x4*)(src + 8);
            const f32x4 f3 = *(const f32x4*)(src + 12);
            f16x8 b0, b1;
#pragma unroll
            for (int t = 0; t < 4; t++) { b0[t] = (f16)f0[t]; b0[4 + t] = (f16)f1[t]; }
#pragma unroll
            for (int t = 0; t < 4; t++) { b1[t] = (f16)f2[t]; b1[4 + t] = (f16)f3[t]; }
            *(f16x8*)&As[srow][skh]     = b0;
            *(f16x8*)&As[srow][skh + 8] = b1;
        }
        {
            const f16* src = &W[(size_t)(n0 + srow) * E_ + k0 + skh];
            *(f16x8*)&Bs[srow][skh]     = *(const f16x8*)(src);
            *(f16x8*)&Bs[srow][skh + 8] = *(const f16x8*)(src + 8);
        }
        __syncthreads();

        f16x8 af[4], bfr[4];
#pragma unroll
        for (int ms = 0; ms < 4; ms++) af[ms]  = *(const f16x8*)&As[wm + ms * 16 + lr][lg * 8];
#pragma unroll
        for (int ns = 0; ns < 4; ns++) bfr[ns] = *(const f16x8*)&Bs[wn + ns * 16 + lr][lg * 8];
#pragma unroll
        for (int ms = 0; ms < 4; ms++)
#pragma unroll
            for (int ns = 0; ns < 4; ns++)
                acc[ms][ns] = MFMA16(af[ms], bfr[ns], acc[ms][ns]);
    }

    const float oscale = (z == 0) ? QSCALE : 1.0f;
#pragma unroll
    for (int ms = 0; ms < 4; ms++) {
        const int mbase = m0 + wm + ms * 16 + lg * 4;
#pragma unroll
        for (int ns = 0; ns < 4; ns++) {
            const int n  = n0 + wn + ns * 16 + lr;
            const float bn = bias[n];
            const int hh = n >> 6, dd = n & 63;
#pragma unroll
            for (int r = 0; r < 4; r++) {
                const float val = (acc[ms][ns][r] + bn) * oscale;
                const int mm = mbase + r;
                const int bb = mm >> 11;
                const int nn = mm & (N_ - 1);
                if (z == 2) {
                    vt[((size_t)(bb * H_ + hh) * D_ + dd) * N_ + nn] = (f16)val;
                } else {
                    f16* dst = (z == 0) ? qh : kh;
                    dst[((size_t)(bb * H_ + hh) * N_ + nn) * D_ + dd] = (f16)val;
                }
            }
        }
    }
}

// ---------------------------------------------------------------------------
// Kernel 3: flash attention, LDS-staged K/V shared by 8 waves, double-buffered.
//  grid (16 q-tiles, 32 b*h); block = 512 = 8 waves; wave owns 16 q-rows.
//  qh/kh: [bh][n][64] f16 (q pre-scaled by QSCALE); vt: [bh][64][n] f16.
// ---------------------------------------------------------------------------
__global__ __launch_bounds__(512) void attn_kernel(
    const f16* __restrict__ qh, const f16* __restrict__ kh,
    const f16* __restrict__ vt, f16* __restrict__ ao)
{
    const int qt = blockIdx.x;          // 0..15
    const int bh = blockIdx.y;          // 0..31
    const int tid = threadIdx.x;
    const int w = tid >> 6, lane = tid & 63;
    const int lr = lane & 15, lg = lane >> 4;

    const f16* qp = qh + (size_t)bh * N_ * D_;
    const f16* kp = kh + (size_t)bh * N_ * D_;
    const f16* vp = vt + (size_t)bh * D_ * N_;

    const int qrow0 = qt * 128 + w * 16;

    const f16x8 qf0 = *(const f16x8*)&qp[(size_t)(qrow0 + lr) * D_ + lg * 8];
    const f16x8 qf1 = *(const f16x8*)&qp[(size_t)(qrow0 + lr) * D_ + 32 + lg * 8];

    // LDS: K tile [kv=64][d=64]+pad, V tile [d=64][kv=64]+pad, double-buffered.
    __shared__ f16 Ks[2][64][72];
    __shared__ f16 Vs[2][64][72];
    __shared__ f16 plds[8][16][72];     // per-wave P transpose buffer

    // staging coords: 512 threads x 16B = one 64x64 f16 tile per instruction
    const int srow   = tid >> 3;        // 0..63
    const int schunk = (tid & 7) * 8;   // f16 column

    f32x4 acc0 = {0.f,0.f,0.f,0.f}, acc1 = {0.f,0.f,0.f,0.f};
    f32x4 acc2 = {0.f,0.f,0.f,0.f}, acc3 = {0.f,0.f,0.f,0.f};
    float mrun[4], lrun[4];
#pragma unroll
    for (int r = 0; r < 4; r++) { mrun[r] = -1e30f; lrun[r] = 0.f; }

    // prologue: tile 0 into regs
    f16x8 kreg = *(const f16x8*)&kp[(size_t)srow * D_ + schunk];
    f16x8 vreg = *(const f16x8*)&vp[(size_t)srow * N_ + schunk];

    constexpr int NT = N_ / 64;         // 32
    int cur = 0;

    for (int t = 0; t < NT; ++t) {
        // write staged regs -> buf[cur]
        *(f16x8*)&Ks[cur][srow][schunk] = kreg;
        *(f16x8*)&Vs[cur][srow][schunk] = vreg;
        // issue next tile's global loads (latency hides under this tile's compute)
        if (t + 1 < NT) {
            kreg = *(const f16x8*)&kp[(size_t)((t + 1) * 64 + srow) * D_ + schunk];
            vreg = *(const f16x8*)&vp[(size_t)srow * N_ + (t + 1) * 64 + schunk];
        }
        __syncthreads();   // buf[cur] writes visible; buf[cur^1] free for next iter

        // ---- S = Q K^T over 4 col-subtiles ----
        f32x4 s0 = {0.f,0.f,0.f,0.f}, s1 = {0.f,0.f,0.f,0.f};
        f32x4 s2 = {0.f,0.f,0.f,0.f}, s3 = {0.f,0.f,0.f,0.f};
        __builtin_amdgcn_s_setprio(1);
#define QKSTEP(c, sc)                                                   \
        {                                                               \
            const f16x8 kf0 = *(const f16x8*)&Ks[cur][(c)*16 + lr][lg*8];      \
            const f16x8 kf1 = *(const f16x8*)&Ks[cur][(c)*16 + lr][32 + lg*8]; \
            sc = MFMA16(qf0, kf0, sc);                                  \
            sc = MFMA16(qf1, kf1, sc);                                  \
        }
        QKSTEP(0, s0) QKSTEP(1, s1) QKSTEP(2, s2) QKSTEP(3, s3)
#undef QKSTEP
        __builtin_amdgcn_s_setprio(0);

        // ---- online softmax in exp2 domain (rows = lg*4+r, cols = lr) ----
        float alpha[4];
#pragma unroll
        for (int r = 0; r < 4; r++) {
            float mx = fmaxf(fmaxf(s0[r], s1[r]), fmaxf(s2[r], s3[r]));
#pragma unroll
            for (int off = 1; off < 16; off <<= 1) mx = fmaxf(mx, __shfl_xor(mx, off));
            const float mnew = fmaxf(mrun[r], mx);
            alpha[r] = __builtin_amdgcn_exp2f(mrun[r] - mnew);
            mrun[r] = mnew;
            const float p0 = __builtin_amdgcn_exp2f(s0[r] - mnew);
            const float p1 = __builtin_amdgcn_exp2f(s1[r] - mnew);
            const float p2 = __builtin_amdgcn_exp2f(s2[r] - mnew);
            const float p3 = __builtin_amdgcn_exp2f(s3[r] - mnew);
            s0[r] = p0; s1[r] = p1; s2[r] = p2; s3[r] = p3;
            float sm = p0 + p1 + p2 + p3;
#pragma unroll
            for (int off = 1; off < 16; off <<= 1) sm += __shfl_xor(sm, off);
            lrun[r] = lrun[r] * alpha[r] + sm;
        }
#pragma unroll
        for (int r = 0; r < 4; r++) {
            acc0[r] *= alpha[r]; acc1[r] *= alpha[r];
            acc2[r] *= alpha[r]; acc3[r] *= alpha[r];
        }

        // ---- P (C-layout) -> per-wave LDS (A-layout source) ----
#pragma unroll
        for (int r = 0; r < 4; r++) {
            plds[w][lg * 4 + r][ 0 + lr] = (f16)s0[r];
            plds[w][lg * 4 + r][16 + lr] = (f16)s1[r];
            plds[w][lg * 4 + r][32 + lr] = (f16)s2[r];
            plds[w][lg * 4 + r][48 + lr] = (f16)s3[r];
        }

        // ---- O += P V ----
        __builtin_amdgcn_s_setprio(1);
#pragma unroll
        for (int kc = 0; kc < 2; kc++) {
            const f16x8 pa  = *(const f16x8*)&plds[w][lr][kc * 32 + lg * 8];
            const f16x8 vf0 = *(const f16x8*)&Vs[cur][ 0 + lr][kc * 32 + lg * 8];
            const f16x8 vf1 = *(const f16x8*)&Vs[cur][16 + lr][kc * 32 + lg * 8];
            const f16x8 vf2 = *(const f16x8*)&Vs[cur][32 + lr][kc * 32 + lg * 8];
            const f16x8 vf3 = *(const f16x8*)&Vs[cur][48 + lr][kc * 32 + lg * 8];
            acc0 = MFMA16(pa, vf0, acc0);
            acc1 = MFMA16(pa, vf1, acc1);
            acc2 = MFMA16(pa, vf2, acc2);
            acc3 = MFMA16(pa, vf3, acc3);
        }
        __builtin_amdgcn_s_setprio(0);

        cur ^= 1;
    }

    // ---- epilogue ----
    const int b = bh >> 4, h = bh & 15;
#pragma unroll
    for (int r = 0; r < 4; r++) {
        const float inv = 1.0f / lrun[r];
        const int qrow = qrow0 + lg * 4 + r;
        f16* dst = &ao[(size_t)(b * N_ + qrow) * E_ + h * 64 + lr];
        dst[ 0] = (f16)(acc0[r] * inv);
        dst[16] = (f16)(acc1[r] * inv);
        dst[32] = (f16)(acc2[r] * inv);
        dst[48] = (f16)(acc3[r] * inv);
    }
}

// ---------------------------------------------------------------------------
// Kernel 4: output GEMM.  out[m,n] = ao[m,:] . Wo[n,:] + bo[n]   (fp32 out)
// ---------------------------------------------------------------------------
__global__ __launch_bounds__(256) void out_gemm(
    const f16* __restrict__ ao, const f16* __restrict__ Wo,
    const float* __restrict__ bo, float* __restrict__ out)
{
    __shared__ f16 As[128][40];
    __shared__ f16 Bs[128][40];

    const int tid  = threadIdx.x;
    const int lane = tid & 63, w = tid >> 6;
    const int lr = lane & 15, lg = lane >> 4;
    const int wm = (w >> 1) * 64, wn = (w & 1) * 64;
    const int m0 = blockIdx.y * 128, n0 = blockIdx.x * 128;

    const int srow = tid >> 1;
    const int skh  = (tid & 1) * 16;

    f32x4 acc[4][4];
#pragma unroll
    for (int i = 0; i < 4; i++)
#pragma unroll
        for (int j = 0; j < 4; j++) acc[i][j] = (f32x4){0.f, 0.f, 0.f, 0.f};

    for (int k0 = 0; k0 < E_; k0 += 32) {
        __syncthreads();
        {
            const f16* src = &ao[(size_t)(m0 + srow) * E_ + k0 + skh];
            *(f16x8*)&As[srow][skh]     = *(const f16x8*)(src);
            *(f16x8*)&As[srow][skh + 8] = *(const f16x8*)(src + 8);
        }
        {
            const f16* src = &Wo[(size_t)(n0 + srow) * E_ + k0 + skh];
            *(f16x8*)&Bs[srow][skh]     = *(const f16x8*)(src);
            *(f16x8*)&Bs[srow][skh + 8] = *(const f16x8*)(src + 8);
        }
        __syncthreads();

        f16x8 af[4], bfr[4];
#pragma unroll
        for (int ms = 0; ms < 4; ms++) af[ms]  = *(const f16x8*)&As[wm + ms * 16 + lr][lg * 8];
#pragma unroll
        for (int ns = 0; ns < 4; ns++) bfr[ns] = *(const f16x8*)&Bs[wn + ns * 16 + lr][lg * 8];
#pragma unroll
        for (int ms = 0; ms < 4; ms++)
#pragma unroll
            for (int ns = 0; ns < 4; ns++)
                acc[ms][ns] = MFMA16(af[ms], bfr[ns], acc[ms][ns]);
    }

#pragma unroll
    for (int ms = 0; ms < 4; ms++) {
        const int mbase = m0 + wm + ms * 16 + lg * 4;
#pragma unroll
        for (int ns = 0; ns < 4; ns++) {
            const int n = n0 + wn + ns * 16 + lr;
            const float bn = bo[n];
#pragma unroll
            for (int r = 0; r < 4; r++) {
                out[(size_t)(mbase + r) * E_ + n] = acc[ms][ns][r] + bn;
            }
        }
    }
}

// ---------------------------------------------------------------------------
extern "C" void kernel_launch(void* const* d_in, const int* in_sizes, int n_in,
                              void* d_out, int out_size, void* d_ws, size_t ws_size,
                              hipStream_t stream) {
    const float* q  = (const float*)d_in[0];
    const float* k  = (const float*)d_in[1];
    const float* v  = (const float*)d_in[2];
    const float* Wq = (const float*)d_in[3];
    const float* bq = (const float*)d_in[4];
    const float* Wk = (const float*)d_in[5];
    const float* bk = (const float*)d_in[6];
    const float* Wv = (const float*)d_in[7];
    const float* bv = (const float*)d_in[8];
    const float* Wo = (const float*)d_in[9];
    const float* bo = (const float*)d_in[10];
    float* out = (float*)d_out;

    char* ws = (char*)d_ws;
    f16* Wb = (f16*)ws;                                   //  8 MB: Wq|Wk|Wv|Wo f16
    f16* qh = (f16*)(ws + (size_t) 8 * 1024 * 1024);      //  8 MB [B,H,N,D]
    f16* kh = (f16*)(ws + (size_t)16 * 1024 * 1024);      //  8 MB [B,H,N,D]
    f16* vt = (f16*)(ws + (size_t)24 * 1024 * 1024);      //  8 MB [B,H,D,N]
    f16* ao = (f16*)(ws + (size_t)32 * 1024 * 1024);      //  8 MB [B,N,E]

    castw_kernel<<<4096, 256, 0, stream>>>(Wq, Wk, Wv, Wo, Wb);
    proj_gemm<<<dim3(8, 32, 3), 256, 0, stream>>>(q, k, v, Wb, bq, bk, bv, qh, kh, vt);
    attn_kernel<<<dim3(16, 32), 512, 0, stream>>>(qh, kh, vt, ao);
    out_gemm<<<dim3(8, 32), 256, 0, stream>>>(ao, Wb + (size_t)3 * E_ * E_, bo, out);
}

// Round 4
// 169.446 us; speedup vs baseline: 1.9727x; 1.2214x over previous
//
#include <hip/hip_runtime.h>

typedef _Float16 f16;
typedef __attribute__((ext_vector_type(2))) _Float16 f16x2;
typedef __attribute__((ext_vector_type(4))) _Float16 f16x4;
typedef __attribute__((ext_vector_type(8))) _Float16 f16x8;
typedef __attribute__((ext_vector_type(4))) float    f32x4;
typedef __attribute__((ext_vector_type(16))) float   f32x16;
typedef __attribute__((ext_vector_type(4))) unsigned u32x4;

static constexpr int B_ = 2, N_ = 2048, E_ = 1024, H_ = 16, D_ = 64;

#define MFMA16(a, b, c) __builtin_amdgcn_mfma_f32_16x16x32_f16(a, b, c, 0, 0, 0)
#define MFMA32(a, b, c) __builtin_amdgcn_mfma_f32_32x32x16_f16(a, b, c, 0, 0, 0)

// q-projection scale: 1/sqrt(D) * log2(e)  (softmax done in exp2 domain)
#define QSCALE 0.18033688011112042f

// ---------------------------------------------------------------------------
// Kernel 1: cast the 4 weight matrices (fp32, [E,E] row-major) to f16.
// ---------------------------------------------------------------------------
__global__ __launch_bounds__(256) void castw_kernel(
    const float* __restrict__ Wq, const float* __restrict__ Wk,
    const float* __restrict__ Wv, const float* __restrict__ Wo,
    f16* __restrict__ dst)
{
    const int i = (blockIdx.x * 256 + threadIdx.x) * 4;
    const int which = i >> 20;                            // E*E = 2^20
    const float* s = (which == 0) ? Wq : (which == 1) ? Wk : (which == 2) ? Wv : Wo;
    const int j = i & (E_ * E_ - 1);
    const f32x4 f = *(const f32x4*)&s[j];
    f16x4 o;
    o[0] = (f16)f[0]; o[1] = (f16)f[1]; o[2] = (f16)f[2]; o[3] = (f16)f[3];
    *(f16x4*)&dst[i] = o;
}

// ---------------------------------------------------------------------------
// Kernel 2: projection GEMM.  C[m,n] = A[m,:] . W[n,:] + bias[n]
//   Epilogue: q -> qh[b,h,n,d] (scaled by QSCALE), k -> kh, v -> vt[b,h,d,n]
// ---------------------------------------------------------------------------
__global__ __launch_bounds__(256) void proj_gemm(
    const float* __restrict__ q, const float* __restrict__ k, const float* __restrict__ v,
    const f16* __restrict__ Wb,
    const float* __restrict__ bq, const float* __restrict__ bk, const float* __restrict__ bv,
    f16* __restrict__ qh, f16* __restrict__ kh, f16* __restrict__ vt)
{
    const int z = blockIdx.z;
    const float* A    = (z == 0) ? q  : (z == 1) ? k  : v;
    const f16*   W    = Wb + (size_t)z * E_ * E_;
    const float* bias = (z == 0) ? bq : (z == 1) ? bk : bv;

    __shared__ f16 As[128][40];
    __shared__ f16 Bs[128][40];

    const int tid  = threadIdx.x;
    const int lane = tid & 63, w = tid >> 6;
    const int lr = lane & 15, lg = lane >> 4;
    const int wm = (w >> 1) * 64, wn = (w & 1) * 64;
    const int m0 = blockIdx.y * 128, n0 = blockIdx.x * 128;

    const int srow = tid >> 1;
    const int skh  = (tid & 1) * 16;

    f32x4 acc[4][4];
#pragma unroll
    for (int i = 0; i < 4; i++)
#pragma unroll
        for (int j = 0; j < 4; j++) acc[i][j] = (f32x4){0.f, 0.f, 0.f, 0.f};

    for (int k0 = 0; k0 < E_; k0 += 32) {
        __syncthreads();
        {
            const float* src = &A[(size_t)(m0 + srow) * E_ + k0 + skh];
            const f32x4 f0 = *(const f32x4*)(src + 0);
            const f32x4 f1 = *(const f32x4*)(src + 4);
            const f32x4 f2 = *(const f32x4*)(src + 8);
            const f32x4 f3 = *(const f32x4*)(src + 12);
            f16x8 b0, b1;
#pragma unroll
            for (int t = 0; t < 4; t++) { b0[t] = (f16)f0[t]; b0[4 + t] = (f16)f1[t]; }
#pragma unroll
            for (int t = 0; t < 4; t++) { b1[t] = (f16)f2[t]; b1[4 + t] = (f16)f3[t]; }
            *(f16x8*)&As[srow][skh]     = b0;
            *(f16x8*)&As[srow][skh + 8] = b1;
        }
        {
            const f16* src = &W[(size_t)(n0 + srow) * E_ + k0 + skh];
            *(f16x8*)&Bs[srow][skh]     = *(const f16x8*)(src);
            *(f16x8*)&Bs[srow][skh + 8] = *(const f16x8*)(src + 8);
        }
        __syncthreads();

        f16x8 af[4], bfr[4];
#pragma unroll
        for (int ms = 0; ms < 4; ms++) af[ms]  = *(const f16x8*)&As[wm + ms * 16 + lr][lg * 8];
#pragma unroll
        for (int ns = 0; ns < 4; ns++) bfr[ns] = *(const f16x8*)&Bs[wn + ns * 16 + lr][lg * 8];
#pragma unroll
        for (int ms = 0; ms < 4; ms++)
#pragma unroll
            for (int ns = 0; ns < 4; ns++)
                acc[ms][ns] = MFMA16(af[ms], bfr[ns], acc[ms][ns]);
    }

    const float oscale = (z == 0) ? QSCALE : 1.0f;
#pragma unroll
    for (int ms = 0; ms < 4; ms++) {
        const int mbase = m0 + wm + ms * 16 + lg * 4;
#pragma unroll
        for (int ns = 0; ns < 4; ns++) {
            const int n  = n0 + wn + ns * 16 + lr;
            const float bn = bias[n];
            const int hh = n >> 6, dd = n & 63;
#pragma unroll
            for (int r = 0; r < 4; r++) {
                const float val = (acc[ms][ns][r] + bn) * oscale;
                const int mm = mbase + r;
                const int bb = mm >> 11;
                const int nn = mm & (N_ - 1);
                if (z == 2) {
                    vt[((size_t)(bb * H_ + hh) * D_ + dd) * N_ + nn] = (f16)val;
                } else {
                    f16* dst = (z == 0) ? qh : kh;
                    dst[((size_t)(bb * H_ + hh) * N_ + nn) * D_ + dd] = (f16)val;
                }
            }
        }
    }
}

// ---------------------------------------------------------------------------
// Kernel 3: flash attention, swapped-QK 32x32 MFMA, in-register softmax.
//  Block = 256 thr = 4 waves; wave owns 32 q-rows (block: 128). Grid 512 (XCD-swz).
//  S^T = mfma(Kfrag, Qfrag): lane holds P[kv-subset][q = lane&31].
//  O^T = mfma(VTfrag, Pfrag): lane holds O^T[d-subset][q = lane&31].
//  K/V LDS tiles [64][64] f16, XOR-16B-slot swizzle, double-buffered.
//  Cross-half traffic via __shfl_xor(.,32) (direction-unambiguous).
// ---------------------------------------------------------------------------
__global__ __launch_bounds__(256) void attn_kernel(
    const f16* __restrict__ qh, const f16* __restrict__ kh,
    const f16* __restrict__ vt, f16* __restrict__ ao)
{
    // bijective XCD swizzle: 512 blocks, 8 XCDs, 64 per XCD -> 4 bh per XCD
    const int bid = blockIdx.x;
    const int swz = (bid & 7) * 64 + (bid >> 3);
    const int qt = swz & 15;            // 16 q-tiles of 128 rows
    const int bh = swz >> 4;            // 0..31

    const int tid = threadIdx.x;
    const int w = tid >> 6, lane = tid & 63;
    const int l31 = lane & 31;
    const bool hi = (lane >> 5) != 0;
    const int hib = hi ? 1 : 0;

    const f16* qp = qh + (size_t)bh * N_ * D_;
    const f16* kp = kh + (size_t)bh * N_ * D_;
    const f16* vp = vt + (size_t)bh * D_ * N_;

    const int qrow = qt * 128 + w * 32 + l31;

    // Q B-frags (col=q=lane&31, k = ks*16 + hi*8 + j), resident all kernel
    f16x8 qf[4];
#pragma unroll
    for (int ks = 0; ks < 4; ks++)
        qf[ks] = *(const f16x8*)&qp[(size_t)qrow * D_ + ks * 16 + hib * 8];

    __shared__ f16 Ks[2][64][64];   // [kv][d], swizzled
    __shared__ f16 Vs[2][64][64];   // [d][kv], swizzled

    // staging: 256 thr x 16B covers half a 64x64 tile; each thread does rows srow, srow+32
    const int srow = tid >> 3;          // 0..31
    const int sch  = tid & 7;
    const int ssl  = (sch ^ (srow & 7)) * 8;   // same for srow+32 ((row&7) preserved)

    const f16* kg0 = kp + (size_t)srow * D_ + sch * 8;
    const f16* kg1 = kg0 + (size_t)32 * D_;
    const f16* vg0 = vp + (size_t)srow * N_ + sch * 8;
    const f16* vg1 = vg0 + (size_t)32 * N_;

    f32x16 oT0 = {0.f,0.f,0.f,0.f,0.f,0.f,0.f,0.f,0.f,0.f,0.f,0.f,0.f,0.f,0.f,0.f};
    f32x16 oT1 = oT0;
    float mrun = -3.0e38f, lrun = 0.f;

    // prologue: tile 0 into regs
    f16x8 kr0 = *(const f16x8*)(kg0);
    f16x8 kr1 = *(const f16x8*)(kg1);
    f16x8 vr0 = *(const f16x8*)(vg0);
    f16x8 vr1 = *(const f16x8*)(vg1);

    constexpr int NT = N_ / 64;         // 32
    int cur = 0;

    for (int t = 0; t < NT; ++t) {
        *(f16x8*)&Ks[cur][srow     ][ssl] = kr0;
        *(f16x8*)&Ks[cur][srow + 32][ssl] = kr1;
        *(f16x8*)&Vs[cur][srow     ][ssl] = vr0;
        *(f16x8*)&Vs[cur][srow + 32][ssl] = vr1;
        if (t + 1 < NT) {
            kr0 = *(const f16x8*)(kg0 + (size_t)(t + 1) * 64 * D_);
            kr1 = *(const f16x8*)(kg1 + (size_t)(t + 1) * 64 * D_);
            vr0 = *(const f16x8*)(vg0 + (t + 1) * 64);
            vr1 = *(const f16x8*)(vg1 + (t + 1) * 64);
        }
        __syncthreads();

        // ---- S^T = K . Q^T : lane holds rows kv=(r&3)+8*(r>>2)+4*hi (+32 for sB), col q=l31
        f32x16 sA = {0.f,0.f,0.f,0.f,0.f,0.f,0.f,0.f,0.f,0.f,0.f,0.f,0.f,0.f,0.f,0.f};
        f32x16 sB = sA;
        __builtin_amdgcn_s_setprio(1);
#pragma unroll
        for (int ks = 0; ks < 4; ks++) {
            const int c = (ks * 2 + hib) ^ (l31 & 7);
            const f16x8 kfA = *(const f16x8*)&Ks[cur][l31     ][c * 8];
            const f16x8 kfB = *(const f16x8*)&Ks[cur][l31 + 32][c * 8];
            sA = MFMA32(kfA, qf[ks], sA);
            sB = MFMA32(kfB, qf[ks], sB);
        }
        __builtin_amdgcn_s_setprio(0);

        // ---- in-register online softmax (q = l31; partner lane l^32 holds other half)
        float tt[16];
#pragma unroll
        for (int r = 0; r < 16; r++) tt[r] = fmaxf(sA[r], sB[r]);
#pragma unroll
        for (int d = 8; d >= 1; d >>= 1)
#pragma unroll
            for (int r = 0; r < d; r++) tt[r] = fmaxf(tt[r], tt[r + d]);
        tt[0] = fmaxf(tt[0], __shfl_xor(tt[0], 32));
        const float mnew = fmaxf(mrun, tt[0]);
        const float alpha = __builtin_amdgcn_exp2f(mrun - mnew);
        mrun = mnew;
        float p0 = 0.f, p1 = 0.f, p2 = 0.f, p3 = 0.f;
#pragma unroll
        for (int r = 0; r < 16; r += 4) {
            sA[r]   = __builtin_amdgcn_exp2f(sA[r]   - mnew); p0 += sA[r];
            sA[r+1] = __builtin_amdgcn_exp2f(sA[r+1] - mnew); p1 += sA[r+1];
            sA[r+2] = __builtin_amdgcn_exp2f(sA[r+2] - mnew); p2 += sA[r+2];
            sA[r+3] = __builtin_amdgcn_exp2f(sA[r+3] - mnew); p3 += sA[r+3];
        }
#pragma unroll
        for (int r = 0; r < 16; r += 4) {
            sB[r]   = __builtin_amdgcn_exp2f(sB[r]   - mnew); p0 += sB[r];
            sB[r+1] = __builtin_amdgcn_exp2f(sB[r+1] - mnew); p1 += sB[r+1];
            sB[r+2] = __builtin_amdgcn_exp2f(sB[r+2] - mnew); p2 += sB[r+2];
            sB[r+3] = __builtin_amdgcn_exp2f(sB[r+3] - mnew); p3 += sB[r+3];
        }
        float lsum = (p0 + p1) + (p2 + p3);
        lsum += __shfl_xor(lsum, 32);
        lrun = lrun * alpha + lsum;
#pragma unroll
        for (int r = 0; r < 16; r++) { oT0[r] *= alpha; oT1[r] *= alpha; }

        // ---- P -> B-frag via cvt_pkrtz + shfl_xor(32) + select; O^T += V^T . P ----
        // Own words (hi=0): w0=(kv c0,c1) w1=(c2,c3) w2=(c8,c9) w3=(c10,c11) within chunk;
        // partner holds the complementary rows. Slot needs kv = hib*8 + j.
        __builtin_amdgcn_s_setprio(1);
#define PVSTEP(PP0,PP1,PP2,PP3,PP4,PP5,PP6,PP7, KSI)                                   \
        {                                                                              \
            const unsigned w0 = __builtin_bit_cast(unsigned, __builtin_amdgcn_cvt_pkrtz(PP0, PP1)); \
            const unsigned w1 = __builtin_bit_cast(unsigned, __builtin_amdgcn_cvt_pkrtz(PP2, PP3)); \
            const unsigned w2 = __builtin_bit_cast(unsigned, __builtin_amdgcn_cvt_pkrtz(PP4, PP5)); \
            const unsigned w3 = __builtin_bit_cast(unsigned, __builtin_amdgcn_cvt_pkrtz(PP6, PP7)); \
            const unsigned x0 = (unsigned)__shfl_xor((int)w0, 32);                     \
            const unsigned x1 = (unsigned)__shfl_xor((int)w1, 32);                     \
            const unsigned x2 = (unsigned)__shfl_xor((int)w2, 32);                     \
            const unsigned x3 = (unsigned)__shfl_xor((int)w3, 32);                     \
            u32x4 pw;                                                                  \
            pw[0] = hi ? x2 : w0;                                                      \
            pw[1] = hi ? x3 : w1;                                                      \
            pw[2] = hi ? w2 : x0;                                                      \
            pw[3] = hi ? w3 : x1;                                                      \
            const f16x8 pa = __builtin_bit_cast(f16x8, pw);                            \
            const int c = ((KSI) * 2 + hib) ^ (l31 & 7);                               \
            const f16x8 vf0 = *(const f16x8*)&Vs[cur][l31     ][c * 8];                \
            const f16x8 vf1 = *(const f16x8*)&Vs[cur][l31 + 32][c * 8];                \
            oT0 = MFMA32(vf0, pa, oT0);                                                \
            oT1 = MFMA32(vf1, pa, oT1);                                                \
        }
        PVSTEP(sA[0],sA[1],sA[2],sA[3],sA[4],sA[5],sA[6],sA[7], 0)
        PVSTEP(sA[8],sA[9],sA[10],sA[11],sA[12],sA[13],sA[14],sA[15], 1)
        PVSTEP(sB[0],sB[1],sB[2],sB[3],sB[4],sB[5],sB[6],sB[7], 2)
        PVSTEP(sB[8],sB[9],sB[10],sB[11],sB[12],sB[13],sB[14],sB[15], 3)
#undef PVSTEP
        __builtin_amdgcn_s_setprio(0);

        cur ^= 1;
    }

    // ---- epilogue: O[q][d] = O^T / lrun;  d = 8g + 4hi + (r&3) (+32 for oT1)
    const float inv = 1.0f / lrun;
    const int b = bh >> 4, h = bh & 15;
    f16* dst = ao + (size_t)(b * N_ + qrow) * E_ + h * 64 + hib * 4;
#pragma unroll
    for (int g = 0; g < 4; g++) {
        f16x4 o0, o1;
#pragma unroll
        for (int j = 0; j < 4; j++) {
            o0[j] = (f16)(oT0[g * 4 + j] * inv);
            o1[j] = (f16)(oT1[g * 4 + j] * inv);
        }
        *(f16x4*)&dst[8 * g]      = o0;
        *(f16x4*)&dst[8 * g + 32] = o1;
    }
}

// ---------------------------------------------------------------------------
// Kernel 4: output GEMM.  out[m,n] = ao[m,:] . Wo[n,:] + bo[n]   (fp32 out)
// ---------------------------------------------------------------------------
__global__ __launch_bounds__(256) void out_gemm(
    const f16* __restrict__ ao, const f16* __restrict__ Wo,
    const float* __restrict__ bo, float* __restrict__ out)
{
    __shared__ f16 As[128][40];
    __shared__ f16 Bs[128][40];

    const int tid  = threadIdx.x;
    const int lane = tid & 63, w = tid >> 6;
    const int lr = lane & 15, lg = lane >> 4;
    const int wm = (w >> 1) * 64, wn = (w & 1) * 64;
    const int m0 = blockIdx.y * 128, n0 = blockIdx.x * 128;

    const int srow = tid >> 1;
    const int skh  = (tid & 1) * 16;

    f32x4 acc[4][4];
#pragma unroll
    for (int i = 0; i < 4; i++)
#pragma unroll
        for (int j = 0; j < 4; j++) acc[i][j] = (f32x4){0.f, 0.f, 0.f, 0.f};

    for (int k0 = 0; k0 < E_; k0 += 32) {
        __syncthreads();
        {
            const f16* src = &ao[(size_t)(m0 + srow) * E_ + k0 + skh];
            *(f16x8*)&As[srow][skh]     = *(const f16x8*)(src);
            *(f16x8*)&As[srow][skh + 8] = *(const f16x8*)(src + 8);
        }
        {
            const f16* src = &Wo[(size_t)(n0 + srow) * E_ + k0 + skh];
            *(f16x8*)&Bs[srow][skh]     = *(const f16x8*)(src);
            *(f16x8*)&Bs[srow][skh + 8] = *(const f16x8*)(src + 8);
        }
        __syncthreads();

        f16x8 af[4], bfr[4];
#pragma unroll
        for (int ms = 0; ms < 4; ms++) af[ms]  = *(const f16x8*)&As[wm + ms * 16 + lr][lg * 8];
#pragma unroll
        for (int ns = 0; ns < 4; ns++) bfr[ns] = *(const f16x8*)&Bs[wn + ns * 16 + lr][lg * 8];
#pragma unroll
        for (int ms = 0; ms < 4; ms++)
#pragma unroll
            for (int ns = 0; ns < 4; ns++)
                acc[ms][ns] = MFMA16(af[ms], bfr[ns], acc[ms][ns]);
    }

#pragma unroll
    for (int ms = 0; ms < 4; ms++) {
        const int mbase = m0 + wm + ms * 16 + lg * 4;
#pragma unroll
        for (int ns = 0; ns < 4; ns++) {
            const int n = n0 + wn + ns * 16 + lr;
            const float bn = bo[n];
#pragma unroll
            for (int r = 0; r < 4; r++) {
                out[(size_t)(mbase + r) * E_ + n] = acc[ms][ns][r] + bn;
            }
        }
    }
}

// ---------------------------------------------------------------------------
extern "C" void kernel_launch(void* const* d_in, const int* in_sizes, int n_in,
                              void* d_out, int out_size, void* d_ws, size_t ws_size,
                              hipStream_t stream) {
    const float* q  = (const float*)d_in[0];
    const float* k  = (const float*)d_in[1];
    const float* v  = (const float*)d_in[2];
    const float* Wq = (const float*)d_in[3];
    const float* bq = (const float*)d_in[4];
    const float* Wk = (const float*)d_in[5];
    const float* bk = (const float*)d_in[6];
    const float* Wv = (const float*)d_in[7];
    const float* bv = (const float*)d_in[8];
    const float* Wo = (const float*)d_in[9];
    const float* bo = (const float*)d_in[10];
    float* out = (float*)d_out;

    char* ws = (char*)d_ws;
    f16* Wb = (f16*)ws;                                   //  8 MB: Wq|Wk|Wv|Wo f16
    f16* qh = (f16*)(ws + (size_t) 8 * 1024 * 1024);      //  8 MB [B,H,N,D]
    f16* kh = (f16*)(ws + (size_t)16 * 1024 * 1024);      //  8 MB [B,H,N,D]
    f16* vt = (f16*)(ws + (size_t)24 * 1024 * 1024);      //  8 MB [B,H,D,N]
    f16* ao = (f16*)(ws + (size_t)32 * 1024 * 1024);      //  8 MB [B,N,E]

    castw_kernel<<<4096, 256, 0, stream>>>(Wq, Wk, Wv, Wo, Wb);
    proj_gemm<<<dim3(8, 32, 3), 256, 0, stream>>>(q, k, v, Wb, bq, bk, bv, qh, kh, vt);
    attn_kernel<<<512, 256, 0, stream>>>(qh, kh, vt, ao);
    out_gemm<<<dim3(8, 32), 256, 0, stream>>>(ao, Wb + (size_t)3 * E_ * E_, bo, out);
}

// Round 5
// 155.042 us; speedup vs baseline: 2.1560x; 1.0929x over previous
//
#include <hip/hip_runtime.h>

typedef _Float16 f16;
typedef __attribute__((ext_vector_type(2))) _Float16 f16x2;
typedef __attribute__((ext_vector_type(4))) _Float16 f16x4;
typedef __attribute__((ext_vector_type(8))) _Float16 f16x8;
typedef __attribute__((ext_vector_type(4))) float    f32x4;
typedef __attribute__((ext_vector_type(16))) float   f32x16;
typedef __attribute__((ext_vector_type(4))) unsigned u32x4;

static constexpr int B_ = 2, N_ = 2048, E_ = 1024, H_ = 16, D_ = 64;

#define MFMA16(a, b, c) __builtin_amdgcn_mfma_f32_16x16x32_f16(a, b, c, 0, 0, 0)
#define MFMA32(a, b, c) __builtin_amdgcn_mfma_f32_32x32x16_f16(a, b, c, 0, 0, 0)

// q-projection scale: 1/sqrt(D) * log2(e)  (softmax done in exp2 domain)
#define QSCALE 0.18033688011112042f

// ---------------------------------------------------------------------------
// Kernel 1: cast the 4 weight matrices (fp32, [E,E] row-major) to f16.
// ---------------------------------------------------------------------------
__global__ __launch_bounds__(256) void castw_kernel(
    const float* __restrict__ Wq, const float* __restrict__ Wk,
    const float* __restrict__ Wv, const float* __restrict__ Wo,
    f16* __restrict__ dst)
{
    const int i = (blockIdx.x * 256 + threadIdx.x) * 4;
    const int which = i >> 20;                            // E*E = 2^20
    const float* s = (which == 0) ? Wq : (which == 1) ? Wk : (which == 2) ? Wv : Wo;
    const int j = i & (E_ * E_ - 1);
    const f32x4 f = *(const f32x4*)&s[j];
    f16x4 o;
    o[0] = (f16)f[0]; o[1] = (f16)f[1]; o[2] = (f16)f[2]; o[3] = (f16)f[3];
    *(f16x4*)&dst[i] = o;
}

// ---------------------------------------------------------------------------
// Kernel 2: projection GEMM.  C[m,n] = A[m,:] . W[n,:] + bias[n]
//   Flat grid 768, XCD-contiguous remap: each XCD owns 12 consecutive m-panels
//   (x8 n-blocks) so an A-panel is fetched into exactly ONE XCD's L2.
//   Epilogue: q -> qh[b,h,n,d] (scaled by QSCALE), k -> kh, v -> vt[b,h,d,n]
// ---------------------------------------------------------------------------
__global__ __launch_bounds__(256) void proj_gemm(
    const float* __restrict__ q, const float* __restrict__ k, const float* __restrict__ v,
    const f16* __restrict__ Wb,
    const float* __restrict__ bq, const float* __restrict__ bk, const float* __restrict__ bv,
    f16* __restrict__ qh, f16* __restrict__ kh, f16* __restrict__ vt)
{
    // XCD-contiguous work remap (768 = 8 XCD * 96)
    const int bid  = blockIdx.x;
    const int lin  = (bid & 7) * 96 + (bid >> 3);
    const int z    = lin >> 8;                 // 256 blocks per z
    const int rem  = lin & 255;
    const int m0   = (rem >> 3) * 128;         // 32 m-panels
    const int n0   = (rem & 7) * 128;          // 8 n-panels

    const float* A    = (z == 0) ? q  : (z == 1) ? k  : v;
    const f16*   W    = Wb + (size_t)z * E_ * E_;
    const float* bias = (z == 0) ? bq : (z == 1) ? bk : bv;

    __shared__ f16 As[128][40];
    __shared__ f16 Bs[128][40];

    const int tid  = threadIdx.x;
    const int lane = tid & 63, w = tid >> 6;
    const int lr = lane & 15, lg = lane >> 4;
    const int wm = (w >> 1) * 64, wn = (w & 1) * 64;

    const int srow = tid >> 1;
    const int skh  = (tid & 1) * 16;

    f32x4 acc[4][4];
#pragma unroll
    for (int i = 0; i < 4; i++)
#pragma unroll
        for (int j = 0; j < 4; j++) acc[i][j] = (f32x4){0.f, 0.f, 0.f, 0.f};

    for (int k0 = 0; k0 < E_; k0 += 32) {
        __syncthreads();
        {
            const float* src = &A[(size_t)(m0 + srow) * E_ + k0 + skh];
            const f32x4 f0 = *(const f32x4*)(src + 0);
            const f32x4 f1 = *(const f32x4*)(src + 4);
            const f32x4 f2 = *(const f32x4*)(src + 8);
            const f32x4 f3 = *(const f32x4*)(src + 12);
            f16x8 b0, b1;
#pragma unroll
            for (int t = 0; t < 4; t++) { b0[t] = (f16)f0[t]; b0[4 + t] = (f16)f1[t]; }
#pragma unroll
            for (int t = 0; t < 4; t++) { b1[t] = (f16)f2[t]; b1[4 + t] = (f16)f3[t]; }
            *(f16x8*)&As[srow][skh]     = b0;
            *(f16x8*)&As[srow][skh + 8] = b1;
        }
        {
            const f16* src = &W[(size_t)(n0 + srow) * E_ + k0 + skh];
            *(f16x8*)&Bs[srow][skh]     = *(const f16x8*)(src);
            *(f16x8*)&Bs[srow][skh + 8] = *(const f16x8*)(src + 8);
        }
        __syncthreads();

        f16x8 af[4], bfr[4];
#pragma unroll
        for (int ms = 0; ms < 4; ms++) af[ms]  = *(const f16x8*)&As[wm + ms * 16 + lr][lg * 8];
#pragma unroll
        for (int ns = 0; ns < 4; ns++) bfr[ns] = *(const f16x8*)&Bs[wn + ns * 16 + lr][lg * 8];
#pragma unroll
        for (int ms = 0; ms < 4; ms++)
#pragma unroll
            for (int ns = 0; ns < 4; ns++)
                acc[ms][ns] = MFMA16(af[ms], bfr[ns], acc[ms][ns]);
    }

    const float oscale = (z == 0) ? QSCALE : 1.0f;
#pragma unroll
    for (int ms = 0; ms < 4; ms++) {
        const int mbase = m0 + wm + ms * 16 + lg * 4;
#pragma unroll
        for (int ns = 0; ns < 4; ns++) {
            const int n  = n0 + wn + ns * 16 + lr;
            const float bn = bias[n];
            const int hh = n >> 6, dd = n & 63;
#pragma unroll
            for (int r = 0; r < 4; r++) {
                const float val = (acc[ms][ns][r] + bn) * oscale;
                const int mm = mbase + r;
                const int bb = mm >> 11;
                const int nn = mm & (N_ - 1);
                if (z == 2) {
                    vt[((size_t)(bb * H_ + hh) * D_ + dd) * N_ + nn] = (f16)val;
                } else {
                    f16* dst = (z == 0) ? qh : kh;
                    dst[((size_t)(bb * H_ + hh) * N_ + nn) * D_ + dd] = (f16)val;
                }
            }
        }
    }
}

// ---------------------------------------------------------------------------
// Kernel 3: flash attention, swapped-QK 32x32 MFMA, in-register softmax,
//  defer-max (skip O-rescale unless tile max grew > 8 in log2 domain).
// ---------------------------------------------------------------------------
__global__ __launch_bounds__(256) void attn_kernel(
    const f16* __restrict__ qh, const f16* __restrict__ kh,
    const f16* __restrict__ vt, f16* __restrict__ ao)
{
    // bijective XCD swizzle: 512 blocks, 8 XCDs, 64 per XCD -> 4 bh per XCD
    const int bid = blockIdx.x;
    const int swz = (bid & 7) * 64 + (bid >> 3);
    const int qt = swz & 15;            // 16 q-tiles of 128 rows
    const int bh = swz >> 4;            // 0..31

    const int tid = threadIdx.x;
    const int w = tid >> 6, lane = tid & 63;
    const int l31 = lane & 31;
    const bool hi = (lane >> 5) != 0;
    const int hib = hi ? 1 : 0;

    const f16* qp = qh + (size_t)bh * N_ * D_;
    const f16* kp = kh + (size_t)bh * N_ * D_;
    const f16* vp = vt + (size_t)bh * D_ * N_;

    const int qrow = qt * 128 + w * 32 + l31;

    f16x8 qf[4];
#pragma unroll
    for (int ks = 0; ks < 4; ks++)
        qf[ks] = *(const f16x8*)&qp[(size_t)qrow * D_ + ks * 16 + hib * 8];

    __shared__ f16 Ks[2][64][64];   // [kv][d], swizzled
    __shared__ f16 Vs[2][64][64];   // [d][kv], swizzled

    const int srow = tid >> 3;          // 0..31
    const int sch  = tid & 7;
    const int ssl  = (sch ^ (srow & 7)) * 8;

    const f16* kg0 = kp + (size_t)srow * D_ + sch * 8;
    const f16* kg1 = kg0 + (size_t)32 * D_;
    const f16* vg0 = vp + (size_t)srow * N_ + sch * 8;
    const f16* vg1 = vg0 + (size_t)32 * N_;

    f32x16 oT0 = {0.f,0.f,0.f,0.f,0.f,0.f,0.f,0.f,0.f,0.f,0.f,0.f,0.f,0.f,0.f,0.f};
    f32x16 oT1 = oT0;
    float mrun = -3.0e38f, lrun = 0.f;

    f16x8 kr0 = *(const f16x8*)(kg0);
    f16x8 kr1 = *(const f16x8*)(kg1);
    f16x8 vr0 = *(const f16x8*)(vg0);
    f16x8 vr1 = *(const f16x8*)(vg1);

    constexpr int NT = N_ / 64;         // 32
    int cur = 0;

    for (int t = 0; t < NT; ++t) {
        *(f16x8*)&Ks[cur][srow     ][ssl] = kr0;
        *(f16x8*)&Ks[cur][srow + 32][ssl] = kr1;
        *(f16x8*)&Vs[cur][srow     ][ssl] = vr0;
        *(f16x8*)&Vs[cur][srow + 32][ssl] = vr1;
        if (t + 1 < NT) {
            kr0 = *(const f16x8*)(kg0 + (size_t)(t + 1) * 64 * D_);
            kr1 = *(const f16x8*)(kg1 + (size_t)(t + 1) * 64 * D_);
            vr0 = *(const f16x8*)(vg0 + (t + 1) * 64);
            vr1 = *(const f16x8*)(vg1 + (t + 1) * 64);
        }
        __syncthreads();

        // ---- S^T = K . Q^T : lane holds rows kv=(r&3)+8*(r>>2)+4*hi (+32 for sB), col q=l31
        f32x16 sA = {0.f,0.f,0.f,0.f,0.f,0.f,0.f,0.f,0.f,0.f,0.f,0.f,0.f,0.f,0.f,0.f};
        f32x16 sB = sA;
        __builtin_amdgcn_s_setprio(1);
#pragma unroll
        for (int ks = 0; ks < 4; ks++) {
            const int c = (ks * 2 + hib) ^ (l31 & 7);
            const f16x8 kfA = *(const f16x8*)&Ks[cur][l31     ][c * 8];
            const f16x8 kfB = *(const f16x8*)&Ks[cur][l31 + 32][c * 8];
            sA = MFMA32(kfA, qf[ks], sA);
            sB = MFMA32(kfB, qf[ks], sB);
        }
        __builtin_amdgcn_s_setprio(0);

        // ---- tile max (tree) + defer-max online softmax ----
        float tt[16];
#pragma unroll
        for (int r = 0; r < 16; r++) tt[r] = fmaxf(sA[r], sB[r]);
#pragma unroll
        for (int d = 8; d >= 1; d >>= 1)
#pragma unroll
            for (int r = 0; r < d; r++) tt[r] = fmaxf(tt[r], tt[r + d]);
        float pmax = fmaxf(tt[0], __shfl_xor(tt[0], 32));

        if (!__all(pmax - mrun <= 8.0f)) {       // rescale only on real max growth
            const float mnew = fmaxf(mrun, pmax);
            const float alpha = __builtin_amdgcn_exp2f(mrun - mnew);
            mrun = mnew;
            lrun *= alpha;
#pragma unroll
            for (int r = 0; r < 16; r++) { oT0[r] *= alpha; oT1[r] *= alpha; }
        }

        float p0 = 0.f, p1 = 0.f, p2 = 0.f, p3 = 0.f;
#pragma unroll
        for (int r = 0; r < 16; r += 4) {
            sA[r]   = __builtin_amdgcn_exp2f(sA[r]   - mrun); p0 += sA[r];
            sA[r+1] = __builtin_amdgcn_exp2f(sA[r+1] - mrun); p1 += sA[r+1];
            sA[r+2] = __builtin_amdgcn_exp2f(sA[r+2] - mrun); p2 += sA[r+2];
            sA[r+3] = __builtin_amdgcn_exp2f(sA[r+3] - mrun); p3 += sA[r+3];
        }
#pragma unroll
        for (int r = 0; r < 16; r += 4) {
            sB[r]   = __builtin_amdgcn_exp2f(sB[r]   - mrun); p0 += sB[r];
            sB[r+1] = __builtin_amdgcn_exp2f(sB[r+1] - mrun); p1 += sB[r+1];
            sB[r+2] = __builtin_amdgcn_exp2f(sB[r+2] - mrun); p2 += sB[r+2];
            sB[r+3] = __builtin_amdgcn_exp2f(sB[r+3] - mrun); p3 += sB[r+3];
        }
        float lsum = (p0 + p1) + (p2 + p3);
        lsum += __shfl_xor(lsum, 32);
        lrun += lsum;

        // ---- P -> B-frag via cvt_pkrtz + shfl_xor(32) + select; O^T += V^T . P ----
        __builtin_amdgcn_s_setprio(1);
#define PVSTEP(PP0,PP1,PP2,PP3,PP4,PP5,PP6,PP7, KSI)                                   \
        {                                                                              \
            const unsigned w0 = __builtin_bit_cast(unsigned, __builtin_amdgcn_cvt_pkrtz(PP0, PP1)); \
            const unsigned w1 = __builtin_bit_cast(unsigned, __builtin_amdgcn_cvt_pkrtz(PP2, PP3)); \
            const unsigned w2 = __builtin_bit_cast(unsigned, __builtin_amdgcn_cvt_pkrtz(PP4, PP5)); \
            const unsigned w3 = __builtin_bit_cast(unsigned, __builtin_amdgcn_cvt_pkrtz(PP6, PP7)); \
            const unsigned x0 = (unsigned)__shfl_xor((int)w0, 32);                     \
            const unsigned x1 = (unsigned)__shfl_xor((int)w1, 32);                     \
            const unsigned x2 = (unsigned)__shfl_xor((int)w2, 32);                     \
            const unsigned x3 = (unsigned)__shfl_xor((int)w3, 32);                     \
            u32x4 pw;                                                                  \
            pw[0] = hi ? x2 : w0;                                                      \
            pw[1] = hi ? x3 : w1;                                                      \
            pw[2] = hi ? w2 : x0;                                                      \
            pw[3] = hi ? w3 : x1;                                                      \
            const f16x8 pa = __builtin_bit_cast(f16x8, pw);                            \
            const int c = ((KSI) * 2 + hib) ^ (l31 & 7);                               \
            const f16x8 vf0 = *(const f16x8*)&Vs[cur][l31     ][c * 8];                \
            const f16x8 vf1 = *(const f16x8*)&Vs[cur][l31 + 32][c * 8];                \
            oT0 = MFMA32(vf0, pa, oT0);                                                \
            oT1 = MFMA32(vf1, pa, oT1);                                                \
        }
        PVSTEP(sA[0],sA[1],sA[2],sA[3],sA[4],sA[5],sA[6],sA[7], 0)
        PVSTEP(sA[8],sA[9],sA[10],sA[11],sA[12],sA[13],sA[14],sA[15], 1)
        PVSTEP(sB[0],sB[1],sB[2],sB[3],sB[4],sB[5],sB[6],sB[7], 2)
        PVSTEP(sB[8],sB[9],sB[10],sB[11],sB[12],sB[13],sB[14],sB[15], 3)
#undef PVSTEP
        __builtin_amdgcn_s_setprio(0);

        cur ^= 1;
    }

    // ---- epilogue: O[q][d] = O^T / lrun ----
    const float inv = 1.0f / lrun;
    const int b = bh >> 4, h = bh & 15;
    f16* dst = ao + (size_t)(b * N_ + qrow) * E_ + h * 64 + hib * 4;
#pragma unroll
    for (int g = 0; g < 4; g++) {
        f16x4 o0, o1;
#pragma unroll
        for (int j = 0; j < 4; j++) {
            o0[j] = (f16)(oT0[g * 4 + j] * inv);
            o1[j] = (f16)(oT1[g * 4 + j] * inv);
        }
        *(f16x4*)&dst[8 * g]      = o0;
        *(f16x4*)&dst[8 * g + 32] = o1;
    }
}

// ---------------------------------------------------------------------------
// Kernel 4: output GEMM.  out[m,n] = ao[m,:] . Wo[n,:] + bo[n]   (fp32 out)
//   Flat grid 256, XCD-contiguous remap (4 m-panels per XCD).
// ---------------------------------------------------------------------------
__global__ __launch_bounds__(256) void out_gemm(
    const f16* __restrict__ ao, const f16* __restrict__ Wo,
    const float* __restrict__ bo, float* __restrict__ out)
{
    __shared__ f16 As[128][40];
    __shared__ f16 Bs[128][40];

    const int bid = blockIdx.x;
    const int lin = (bid & 7) * 32 + (bid >> 3);
    const int m0  = (lin >> 3) * 128;
    const int n0  = (lin & 7) * 128;

    const int tid  = threadIdx.x;
    const int lane = tid & 63, w = tid >> 6;
    const int lr = lane & 15, lg = lane >> 4;
    const int wm = (w >> 1) * 64, wn = (w & 1) * 64;

    const int srow = tid >> 1;
    const int skh  = (tid & 1) * 16;

    f32x4 acc[4][4];
#pragma unroll
    for (int i = 0; i < 4; i++)
#pragma unroll
        for (int j = 0; j < 4; j++) acc[i][j] = (f32x4){0.f, 0.f, 0.f, 0.f};

    for (int k0 = 0; k0 < E_; k0 += 32) {
        __syncthreads();
        {
            const f16* src = &ao[(size_t)(m0 + srow) * E_ + k0 + skh];
            *(f16x8*)&As[srow][skh]     = *(const f16x8*)(src);
            *(f16x8*)&As[srow][skh + 8] = *(const f16x8*)(src + 8);
        }
        {
            const f16* src = &Wo[(size_t)(n0 + srow) * E_ + k0 + skh];
            *(f16x8*)&Bs[srow][skh]     = *(const f16x8*)(src);
            *(f16x8*)&Bs[srow][skh + 8] = *(const f16x8*)(src + 8);
        }
        __syncthreads();

        f16x8 af[4], bfr[4];
#pragma unroll
        for (int ms = 0; ms < 4; ms++) af[ms]  = *(const f16x8*)&As[wm + ms * 16 + lr][lg * 8];
#pragma unroll
        for (int ns = 0; ns < 4; ns++) bfr[ns] = *(const f16x8*)&Bs[wn + ns * 16 + lr][lg * 8];
#pragma unroll
        for (int ms = 0; ms < 4; ms++)
#pragma unroll
            for (int ns = 0; ns < 4; ns++)
                acc[ms][ns] = MFMA16(af[ms], bfr[ns], acc[ms][ns]);
    }

#pragma unroll
    for (int ms = 0; ms < 4; ms++) {
        const int mbase = m0 + wm + ms * 16 + lg * 4;
#pragma unroll
        for (int ns = 0; ns < 4; ns++) {
            const int n = n0 + wn + ns * 16 + lr;
            const float bn = bo[n];
#pragma unroll
            for (int r = 0; r < 4; r++) {
                out[(size_t)(mbase + r) * E_ + n] = acc[ms][ns][r] + bn;
            }
        }
    }
}

// ---------------------------------------------------------------------------
extern "C" void kernel_launch(void* const* d_in, const int* in_sizes, int n_in,
                              void* d_out, int out_size, void* d_ws, size_t ws_size,
                              hipStream_t stream) {
    const float* q  = (const float*)d_in[0];
    const float* k  = (const float*)d_in[1];
    const float* v  = (const float*)d_in[2];
    const float* Wq = (const float*)d_in[3];
    const float* bq = (const float*)d_in[4];
    const float* Wk = (const float*)d_in[5];
    const float* bk = (const float*)d_in[6];
    const float* Wv = (const float*)d_in[7];
    const float* bv = (const float*)d_in[8];
    const float* Wo = (const float*)d_in[9];
    const float* bo = (const float*)d_in[10];
    float* out = (float*)d_out;

    char* ws = (char*)d_ws;
    f16* Wb = (f16*)ws;                                   //  8 MB: Wq|Wk|Wv|Wo f16
    f16* qh = (f16*)(ws + (size_t) 8 * 1024 * 1024);      //  8 MB [B,H,N,D]
    f16* kh = (f16*)(ws + (size_t)16 * 1024 * 1024);      //  8 MB [B,H,N,D]
    f16* vt = (f16*)(ws + (size_t)24 * 1024 * 1024);      //  8 MB [B,H,D,N]
    f16* ao = (f16*)(ws + (size_t)32 * 1024 * 1024);      //  8 MB [B,N,E]

    castw_kernel<<<4096, 256, 0, stream>>>(Wq, Wk, Wv, Wo, Wb);
    proj_gemm<<<768, 256, 0, stream>>>(q, k, v, Wb, bq, bk, bv, qh, kh, vt);
    attn_kernel<<<512, 256, 0, stream>>>(qh, kh, vt, ao);
    out_gemm<<<256, 256, 0, stream>>>(ao, Wb + (size_t)3 * E_ * E_, bo, out);
}

// Round 6
// 149.712 us; speedup vs baseline: 2.2328x; 1.0356x over previous
//
#include <hip/hip_runtime.h>

typedef _Float16 f16;
typedef __attribute__((ext_vector_type(2))) _Float16 f16x2;
typedef __attribute__((ext_vector_type(4))) _Float16 f16x4;
typedef __attribute__((ext_vector_type(8))) _Float16 f16x8;
typedef __attribute__((ext_vector_type(4))) float    f32x4;
typedef __attribute__((ext_vector_type(16))) float   f32x16;
typedef __attribute__((ext_vector_type(4))) unsigned u32x4;

static constexpr int B_ = 2, N_ = 2048, E_ = 1024, H_ = 16, D_ = 64;
static constexpr int M_ = B_ * N_;   // 4096

#define MFMA16(a, b, c) __builtin_amdgcn_mfma_f32_16x16x32_f16(a, b, c, 0, 0, 0)
#define MFMA32(a, b, c) __builtin_amdgcn_mfma_f32_32x32x16_f16(a, b, c, 0, 0, 0)

// q-projection scale: 1/sqrt(D) * log2(e)  (softmax done in exp2 domain)
#define QSCALE 0.18033688011112042f

// async global(16B/lane) -> LDS (wave-uniform base + lane*16)
__device__ __forceinline__ void gload_lds16(const f16* g, f16* l) {
    typedef __attribute__((address_space(1))) const unsigned gu32;
    typedef __attribute__((address_space(3))) unsigned       lu32;
    __builtin_amdgcn_global_load_lds((gu32*)g, (lu32*)l, 16, 0, 0);
}

// ---------------------------------------------------------------------------
// Kernel 1: cast weights (4*E*E) AND q/k/v (3*M*E) fp32 -> f16 into one flat
// region: [Wq|Wk|Wv|Wo | q|k|v].
// ---------------------------------------------------------------------------
__global__ __launch_bounds__(256) void cast_all(
    const float* __restrict__ Wq, const float* __restrict__ Wk,
    const float* __restrict__ Wv, const float* __restrict__ Wo,
    const float* __restrict__ q, const float* __restrict__ k,
    const float* __restrict__ v, f16* __restrict__ dst)
{
    const int i = (blockIdx.x * 256 + threadIdx.x) * 4;
    const float* s;
    int j;
    if (i < 4 * E_ * E_) {
        const int which = i >> 20;                        // E*E = 2^20
        s = (which == 0) ? Wq : (which == 1) ? Wk : (which == 2) ? Wv : Wo;
        j = i & (E_ * E_ - 1);
    } else {
        const int t = i - 4 * E_ * E_;
        const int which = t >> 22;                        // M*E = 2^22
        s = (which == 0) ? q : (which == 1) ? k : v;
        j = t & (M_ * E_ - 1);
    }
    const f32x4 f = *(const f32x4*)&s[j];
    f16x4 o;
    o[0] = (f16)f[0]; o[1] = (f16)f[1]; o[2] = (f16)f[2]; o[3] = (f16)f[3];
    *(f16x4*)&dst[i] = o;
}

// ---------------------------------------------------------------------------
// Kernel 2: projection GEMM, m97-structure (global_load_lds, linear LDS,
//   XOR-chunk swizzle via pre-swizzled global source).
//   C[m,n] = A[m,:] . W[n,:] + bias[n]; A,W f16.
//   Flat grid 768, XCD-contiguous remap.
//   Epilogue: q -> qh[b,h,n,d] (scaled by QSCALE), k -> kh, v -> vt[b,h,d,n]
// ---------------------------------------------------------------------------
__global__ __launch_bounds__(256) void proj_gemm(
    const f16* __restrict__ Aall, const f16* __restrict__ Wb,
    const float* __restrict__ bq, const float* __restrict__ bk, const float* __restrict__ bv,
    f16* __restrict__ qh, f16* __restrict__ kh, f16* __restrict__ vt)
{
    const int bid  = blockIdx.x;
    const int lin  = (bid & 7) * 96 + (bid >> 3);
    const int z    = lin >> 8;
    const int rem  = lin & 255;
    const int m0   = (rem >> 3) * 128;
    const int n0   = (rem & 7) * 128;

    const f16* A    = Aall + (size_t)z * M_ * E_;
    const f16* W    = Wb + (size_t)z * E_ * E_;
    const float* bias = (z == 0) ? bq : (z == 1) ? bk : bv;

    __shared__ f16 As[128][32];   // linear (global_load_lds requirement)
    __shared__ f16 Bs[128][32];

    const int tid  = threadIdx.x;
    const int lane = tid & 63, w = tid >> 6;
    const int lr = lane & 15, lg = lane >> 4;
    const int wm = (w >> 1) * 64, wn = (w & 1) * 64;

    // staging: lane l covers LDS row base+(l>>2), chunk l&3; global chunk
    // pre-swizzled so LDS[row][c] holds global chunk c ^ ((row>>1)&3).
    const int gch = ((lane & 3) ^ ((lane >> 3) & 3)) * 8;
    const f16* ag = A + (size_t)(m0 + w * 32 + (lane >> 2)) * E_ + gch;
    const f16* bg = W + (size_t)(n0 + w * 32 + (lane >> 2)) * E_ + gch;
    f16* al0 = &As[w * 32][0];
    f16* al1 = &As[w * 32 + 16][0];
    f16* bl0 = &Bs[w * 32][0];
    f16* bl1 = &Bs[w * 32 + 16][0];

    // frag-read chunk (swizzled): lg ^ ((lr>>1)&3)
    const int ca = (lg ^ ((lr >> 1) & 3)) * 8;

    f32x4 acc[4][4];
#pragma unroll
    for (int i = 0; i < 4; i++)
#pragma unroll
        for (int j = 0; j < 4; j++) acc[i][j] = (f32x4){0.f, 0.f, 0.f, 0.f};

    for (int t = 0; t < E_ / 32; ++t) {
        __syncthreads();                       // prev iter's ds_reads done
        gload_lds16(ag,                 al0);
        gload_lds16(ag + 16 * E_,       al1);
        gload_lds16(bg,                 bl0);
        gload_lds16(bg + 16 * E_,       bl1);
        ag += 32; bg += 32;
        __syncthreads();                       // vmcnt(0) drain -> data ready

        f16x8 af[4], bfr[4];
#pragma unroll
        for (int ms = 0; ms < 4; ms++) af[ms]  = *(const f16x8*)&As[wm + ms * 16 + lr][ca];
#pragma unroll
        for (int ns = 0; ns < 4; ns++) bfr[ns] = *(const f16x8*)&Bs[wn + ns * 16 + lr][ca];
        __builtin_amdgcn_s_setprio(1);
#pragma unroll
        for (int ms = 0; ms < 4; ms++)
#pragma unroll
            for (int ns = 0; ns < 4; ns++)
                acc[ms][ns] = MFMA16(af[ms], bfr[ns], acc[ms][ns]);
        __builtin_amdgcn_s_setprio(0);
    }

    const float oscale = (z == 0) ? QSCALE : 1.0f;
#pragma unroll
    for (int ms = 0; ms < 4; ms++) {
        const int mbase = m0 + wm + ms * 16 + lg * 4;
#pragma unroll
        for (int ns = 0; ns < 4; ns++) {
            const int n  = n0 + wn + ns * 16 + lr;
            const float bn = bias[n];
            const int hh = n >> 6, dd = n & 63;
#pragma unroll
            for (int r = 0; r < 4; r++) {
                const float val = (acc[ms][ns][r] + bn) * oscale;
                const int mm = mbase + r;
                const int bb = mm >> 11;
                const int nn = mm & (N_ - 1);
                if (z == 2) {
                    vt[((size_t)(bb * H_ + hh) * D_ + dd) * N_ + nn] = (f16)val;
                } else {
                    f16* dst = (z == 0) ? qh : kh;
                    dst[((size_t)(bb * H_ + hh) * N_ + nn) * D_ + dd] = (f16)val;
                }
            }
        }
    }
}

// ---------------------------------------------------------------------------
// Kernel 3: flash attention, swapped-QK 32x32 MFMA, in-register softmax,
//  defer-max. (unchanged from R5)
// ---------------------------------------------------------------------------
__global__ __launch_bounds__(256) void attn_kernel(
    const f16* __restrict__ qh, const f16* __restrict__ kh,
    const f16* __restrict__ vt, f16* __restrict__ ao)
{
    const int bid = blockIdx.x;
    const int swz = (bid & 7) * 64 + (bid >> 3);
    const int qt = swz & 15;
    const int bh = swz >> 4;

    const int tid = threadIdx.x;
    const int w = tid >> 6, lane = tid & 63;
    const int l31 = lane & 31;
    const bool hi = (lane >> 5) != 0;
    const int hib = hi ? 1 : 0;

    const f16* qp = qh + (size_t)bh * N_ * D_;
    const f16* kp = kh + (size_t)bh * N_ * D_;
    const f16* vp = vt + (size_t)bh * D_ * N_;

    const int qrow = qt * 128 + w * 32 + l31;

    f16x8 qf[4];
#pragma unroll
    for (int ks = 0; ks < 4; ks++)
        qf[ks] = *(const f16x8*)&qp[(size_t)qrow * D_ + ks * 16 + hib * 8];

    __shared__ f16 Ks[2][64][64];
    __shared__ f16 Vs[2][64][64];

    const int srow = tid >> 3;
    const int sch  = tid & 7;
    const int ssl  = (sch ^ (srow & 7)) * 8;

    const f16* kg0 = kp + (size_t)srow * D_ + sch * 8;
    const f16* kg1 = kg0 + (size_t)32 * D_;
    const f16* vg0 = vp + (size_t)srow * N_ + sch * 8;
    const f16* vg1 = vg0 + (size_t)32 * N_;

    f32x16 oT0 = {0.f,0.f,0.f,0.f,0.f,0.f,0.f,0.f,0.f,0.f,0.f,0.f,0.f,0.f,0.f,0.f};
    f32x16 oT1 = oT0;
    float mrun = -3.0e38f, lrun = 0.f;

    f16x8 kr0 = *(const f16x8*)(kg0);
    f16x8 kr1 = *(const f16x8*)(kg1);
    f16x8 vr0 = *(const f16x8*)(vg0);
    f16x8 vr1 = *(const f16x8*)(vg1);

    constexpr int NT = N_ / 64;
    int cur = 0;

    for (int t = 0; t < NT; ++t) {
        *(f16x8*)&Ks[cur][srow     ][ssl] = kr0;
        *(f16x8*)&Ks[cur][srow + 32][ssl] = kr1;
        *(f16x8*)&Vs[cur][srow     ][ssl] = vr0;
        *(f16x8*)&Vs[cur][srow + 32][ssl] = vr1;
        if (t + 1 < NT) {
            kr0 = *(const f16x8*)(kg0 + (size_t)(t + 1) * 64 * D_);
            kr1 = *(const f16x8*)(kg1 + (size_t)(t + 1) * 64 * D_);
            vr0 = *(const f16x8*)(vg0 + (t + 1) * 64);
            vr1 = *(const f16x8*)(vg1 + (t + 1) * 64);
        }
        __syncthreads();

        f32x16 sA = {0.f,0.f,0.f,0.f,0.f,0.f,0.f,0.f,0.f,0.f,0.f,0.f,0.f,0.f,0.f,0.f};
        f32x16 sB = sA;
        __builtin_amdgcn_s_setprio(1);
#pragma unroll
        for (int ks = 0; ks < 4; ks++) {
            const int c = (ks * 2 + hib) ^ (l31 & 7);
            const f16x8 kfA = *(const f16x8*)&Ks[cur][l31     ][c * 8];
            const f16x8 kfB = *(const f16x8*)&Ks[cur][l31 + 32][c * 8];
            sA = MFMA32(kfA, qf[ks], sA);
            sB = MFMA32(kfB, qf[ks], sB);
        }
        __builtin_amdgcn_s_setprio(0);

        float tt[16];
#pragma unroll
        for (int r = 0; r < 16; r++) tt[r] = fmaxf(sA[r], sB[r]);
#pragma unroll
        for (int d = 8; d >= 1; d >>= 1)
#pragma unroll
            for (int r = 0; r < d; r++) tt[r] = fmaxf(tt[r], tt[r + d]);
        float pmax = fmaxf(tt[0], __shfl_xor(tt[0], 32));

        if (!__all(pmax - mrun <= 8.0f)) {
            const float mnew = fmaxf(mrun, pmax);
            const float alpha = __builtin_amdgcn_exp2f(mrun - mnew);
            mrun = mnew;
            lrun *= alpha;
#pragma unroll
            for (int r = 0; r < 16; r++) { oT0[r] *= alpha; oT1[r] *= alpha; }
        }

        float p0 = 0.f, p1 = 0.f, p2 = 0.f, p3 = 0.f;
#pragma unroll
        for (int r = 0; r < 16; r += 4) {
            sA[r]   = __builtin_amdgcn_exp2f(sA[r]   - mrun); p0 += sA[r];
            sA[r+1] = __builtin_amdgcn_exp2f(sA[r+1] - mrun); p1 += sA[r+1];
            sA[r+2] = __builtin_amdgcn_exp2f(sA[r+2] - mrun); p2 += sA[r+2];
            sA[r+3] = __builtin_amdgcn_exp2f(sA[r+3] - mrun); p3 += sA[r+3];
        }
#pragma unroll
        for (int r = 0; r < 16; r += 4) {
            sB[r]   = __builtin_amdgcn_exp2f(sB[r]   - mrun); p0 += sB[r];
            sB[r+1] = __builtin_amdgcn_exp2f(sB[r+1] - mrun); p1 += sB[r+1];
            sB[r+2] = __builtin_amdgcn_exp2f(sB[r+2] - mrun); p2 += sB[r+2];
            sB[r+3] = __builtin_amdgcn_exp2f(sB[r+3] - mrun); p3 += sB[r+3];
        }
        float lsum = (p0 + p1) + (p2 + p3);
        lsum += __shfl_xor(lsum, 32);
        lrun += lsum;

        __builtin_amdgcn_s_setprio(1);
#define PVSTEP(PP0,PP1,PP2,PP3,PP4,PP5,PP6,PP7, KSI)                                   \
        {                                                                              \
            const unsigned w0 = __builtin_bit_cast(unsigned, __builtin_amdgcn_cvt_pkrtz(PP0, PP1)); \
            const unsigned w1 = __builtin_bit_cast(unsigned, __builtin_amdgcn_cvt_pkrtz(PP2, PP3)); \
            const unsigned w2 = __builtin_bit_cast(unsigned, __builtin_amdgcn_cvt_pkrtz(PP4, PP5)); \
            const unsigned w3 = __builtin_bit_cast(unsigned, __builtin_amdgcn_cvt_pkrtz(PP6, PP7)); \
            const unsigned x0 = (unsigned)__shfl_xor((int)w0, 32);                     \
            const unsigned x1 = (unsigned)__shfl_xor((int)w1, 32);                     \
            const unsigned x2 = (unsigned)__shfl_xor((int)w2, 32);                     \
            const unsigned x3 = (unsigned)__shfl_xor((int)w3, 32);                     \
            u32x4 pw;                                                                  \
            pw[0] = hi ? x2 : w0;                                                      \
            pw[1] = hi ? x3 : w1;                                                      \
            pw[2] = hi ? w2 : x0;                                                      \
            pw[3] = hi ? w3 : x1;                                                      \
            const f16x8 pa = __builtin_bit_cast(f16x8, pw);                            \
            const int c = ((KSI) * 2 + hib) ^ (l31 & 7);                               \
            const f16x8 vf0 = *(const f16x8*)&Vs[cur][l31     ][c * 8];                \
            const f16x8 vf1 = *(const f16x8*)&Vs[cur][l31 + 32][c * 8];                \
            oT0 = MFMA32(vf0, pa, oT0);                                                \
            oT1 = MFMA32(vf1, pa, oT1);                                                \
        }
        PVSTEP(sA[0],sA[1],sA[2],sA[3],sA[4],sA[5],sA[6],sA[7], 0)
        PVSTEP(sA[8],sA[9],sA[10],sA[11],sA[12],sA[13],sA[14],sA[15], 1)
        PVSTEP(sB[0],sB[1],sB[2],sB[3],sB[4],sB[5],sB[6],sB[7], 2)
        PVSTEP(sB[8],sB[9],sB[10],sB[11],sB[12],sB[13],sB[14],sB[15], 3)
#undef PVSTEP
        __builtin_amdgcn_s_setprio(0);

        cur ^= 1;
    }

    const float inv = 1.0f / lrun;
    const int b = bh >> 4, h = bh & 15;
    f16* dst = ao + (size_t)(b * N_ + qrow) * E_ + h * 64 + hib * 4;
#pragma unroll
    for (int g = 0; g < 4; g++) {
        f16x4 o0, o1;
#pragma unroll
        for (int j = 0; j < 4; j++) {
            o0[j] = (f16)(oT0[g * 4 + j] * inv);
            o1[j] = (f16)(oT1[g * 4 + j] * inv);
        }
        *(f16x4*)&dst[8 * g]      = o0;
        *(f16x4*)&dst[8 * g + 32] = o1;
    }
}

// ---------------------------------------------------------------------------
// Kernel 4: output GEMM, m97-structure.  out[m,n] = ao[m,:].Wo[n,:] + bo[n]
//   Flat grid 256, XCD-contiguous remap. fp32 output.
// ---------------------------------------------------------------------------
__global__ __launch_bounds__(256) void out_gemm(
    const f16* __restrict__ ao, const f16* __restrict__ Wo,
    const float* __restrict__ bo, float* __restrict__ out)
{
    __shared__ f16 As[128][32];
    __shared__ f16 Bs[128][32];

    const int bid = blockIdx.x;
    const int lin = (bid & 7) * 32 + (bid >> 3);
    const int m0  = (lin >> 3) * 128;
    const int n0  = (lin & 7) * 128;

    const int tid  = threadIdx.x;
    const int lane = tid & 63, w = tid >> 6;
    const int lr = lane & 15, lg = lane >> 4;
    const int wm = (w >> 1) * 64, wn = (w & 1) * 64;

    const int gch = ((lane & 3) ^ ((lane >> 3) & 3)) * 8;
    const f16* ag = ao + (size_t)(m0 + w * 32 + (lane >> 2)) * E_ + gch;
    const f16* bg = Wo + (size_t)(n0 + w * 32 + (lane >> 2)) * E_ + gch;
    f16* al0 = &As[w * 32][0];
    f16* al1 = &As[w * 32 + 16][0];
    f16* bl0 = &Bs[w * 32][0];
    f16* bl1 = &Bs[w * 32 + 16][0];

    const int ca = (lg ^ ((lr >> 1) & 3)) * 8;

    f32x4 acc[4][4];
#pragma unroll
    for (int i = 0; i < 4; i++)
#pragma unroll
        for (int j = 0; j < 4; j++) acc[i][j] = (f32x4){0.f, 0.f, 0.f, 0.f};

    for (int t = 0; t < E_ / 32; ++t) {
        __syncthreads();
        gload_lds16(ag,            al0);
        gload_lds16(ag + 16 * E_,  al1);
        gload_lds16(bg,            bl0);
        gload_lds16(bg + 16 * E_,  bl1);
        ag += 32; bg += 32;
        __syncthreads();

        f16x8 af[4], bfr[4];
#pragma unroll
        for (int ms = 0; ms < 4; ms++) af[ms]  = *(const f16x8*)&As[wm + ms * 16 + lr][ca];
#pragma unroll
        for (int ns = 0; ns < 4; ns++) bfr[ns] = *(const f16x8*)&Bs[wn + ns * 16 + lr][ca];
        __builtin_amdgcn_s_setprio(1);
#pragma unroll
        for (int ms = 0; ms < 4; ms++)
#pragma unroll
            for (int ns = 0; ns < 4; ns++)
                acc[ms][ns] = MFMA16(af[ms], bfr[ns], acc[ms][ns]);
        __builtin_amdgcn_s_setprio(0);
    }

#pragma unroll
    for (int ms = 0; ms < 4; ms++) {
        const int mbase = m0 + wm + ms * 16 + lg * 4;
#pragma unroll
        for (int ns = 0; ns < 4; ns++) {
            const int n = n0 + wn + ns * 16 + lr;
            const float bn = bo[n];
#pragma unroll
            for (int r = 0; r < 4; r++) {
                out[(size_t)(mbase + r) * E_ + n] = acc[ms][ns][r] + bn;
            }
        }
    }
}

// ---------------------------------------------------------------------------
extern "C" void kernel_launch(void* const* d_in, const int* in_sizes, int n_in,
                              void* d_out, int out_size, void* d_ws, size_t ws_size,
                              hipStream_t stream) {
    const float* q  = (const float*)d_in[0];
    const float* k  = (const float*)d_in[1];
    const float* v  = (const float*)d_in[2];
    const float* Wq = (const float*)d_in[3];
    const float* bq = (const float*)d_in[4];
    const float* Wk = (const float*)d_in[5];
    const float* bk = (const float*)d_in[6];
    const float* Wv = (const float*)d_in[7];
    const float* bv = (const float*)d_in[8];
    const float* Wo = (const float*)d_in[9];
    const float* bo = (const float*)d_in[10];
    float* out = (float*)d_out;

    char* ws = (char*)d_ws;
    // [0,32MiB): f16 cast region = Wq|Wk|Wv|Wo (4*E*E) then q|k|v (3*M*E)
    f16* cast = (f16*)ws;
    f16* Wb   = cast;
    f16* Aall = cast + (size_t)4 * E_ * E_;
    f16* qh = (f16*)(ws + (size_t)32 * 1024 * 1024);
    f16* kh = (f16*)(ws + (size_t)40 * 1024 * 1024);
    f16* vt = (f16*)(ws + (size_t)48 * 1024 * 1024);
    f16* ao = (f16*)(ws + (size_t)56 * 1024 * 1024);

    // (4*E*E + 3*M*E) / (256*4) = 16384 blocks
    cast_all<<<16384, 256, 0, stream>>>(Wq, Wk, Wv, Wo, q, k, v, cast);
    proj_gemm<<<768, 256, 0, stream>>>(Aall, Wb, bq, bk, bv, qh, kh, vt);
    attn_kernel<<<512, 256, 0, stream>>>(qh, kh, vt, ao);
    out_gemm<<<256, 256, 0, stream>>>(ao, Wb + (size_t)3 * E_ * E_, bo, out);
}